// Round 7
// baseline (717.017 us; speedup 1.0000x reference)
//
#include <hip/hip_runtime.h>
#include <stdint.h>

// Sizes (fixed by the problem)
#define NB 256
#define NS 64
#define NR 256
#define NV 2000
#define NC 10
#define NK 6
#define ND 256

typedef __attribute__((ext_vector_type(8))) short bf16x8;
typedef __attribute__((ext_vector_type(4))) float f32x4;

__device__ __forceinline__ float bf2f(uint16_t u) {
  return __uint_as_float(((uint32_t)u) << 16);
}
__device__ __forceinline__ uint16_t f2bf(float f) {
  uint32_t x = __float_as_uint(f);
  x += 0x7FFFu + ((x >> 16) & 1u);
  return (uint16_t)(x >> 16);
}

// ---------------------------------------------------------------------------
// k_prep: block 0 = adjacency dtype-detect + bitmask + neighbor lists + class
//         lists + member index; blocks 1..10 = ud2/us2 = W2[c] @ a2{d,s}
// ---------------------------------------------------------------------------
__global__ void k_prep(const void* __restrict__ adj_raw, const int* __restrict__ mask,
                       const float* __restrict__ W2, const float* __restrict__ a2s,
                       const float* __restrict__ a2d,
                       uint32_t* __restrict__ adjbits, int* __restrict__ cls,
                       int* __restrict__ lists, int* __restrict__ cnt,
                       int* __restrict__ deg, uint8_t* __restrict__ nbr,
                       int8_t* __restrict__ midx,
                       float* __restrict__ ud2, float* __restrict__ us2)
{
  int tid = threadIdx.x;
  if (blockIdx.x == 0) {
    __shared__ int s_is4;
    if (tid == 0) s_is4 = 1;
    __syncthreads();
    const uint32_t* u = (const uint32_t*)adj_raw;
    int ok = 1;
    for (int idx = tid; idx < 16384; idx += 256) {
      uint32_t v = u[idx];
      if (!(v == 0u || v == 1u || v == 0x3F800000u)) ok = 0;
    }
    if (!ok) atomicAnd(&s_is4, 0);
    __syncthreads();
    int is4 = s_is4;
    const uint8_t* b8 = (const uint8_t*)adj_raw;
    int dg = 0;
    for (int w = 0; w < 8; ++w) {
      uint32_t word = 0;
      for (int jb = 0; jb < 32; ++jb) {
        int j = w * 32 + jb;
        int bit = is4 ? (u[tid * 256 + j] != 0u) : (b8[tid * 256 + j] != 0);
        if (bit) {
          word |= (1u << jb);
          if (dg < 64) nbr[tid * 64 + dg] = (uint8_t)j;
          dg++;
        }
      }
      adjbits[tid * 8 + w] = word;
    }
    deg[tid] = (dg > 64) ? 64 : dg;
    int c = 0;
    for (int cc = 0; cc < NC; ++cc) if (mask[cc * 256 + tid] != 0) c = cc;
    cls[tid] = c;
    __syncthreads();
    if (tid == 0) {
      int cn[NC];
      for (int i = 0; i < NC; ++i) cn[i] = 0;
      for (int r = 0; r < 256; ++r) {
        int cc = cls[r];
        if (cn[cc] < 64) lists[cc * 64 + cn[cc]] = r;
        cn[cc]++;
      }
      for (int i = 0; i < NC; ++i) cnt[i] = (cn[i] > 64) ? 64 : cn[i];
      for (int i = 0; i < NC * 256; ++i) midx[i] = -1;
      for (int cc = 0; cc < NC; ++cc)
        for (int i = 0; i < cnt[cc]; ++i)
          midx[cc * 256 + lists[cc * 64 + i]] = (int8_t)i;
    }
  } else {
    int c = blockIdx.x - 1;
    if (tid < 128) {
      float s1 = 0.f, s2 = 0.f;
      for (int g = 0; g < 64; ++g) {
        float w = W2[(c * 128 + tid) * 64 + g];
        s1 += w * a2d[c * 64 + g];
        s2 += w * a2s[c * 64 + g];
      }
      ud2[c * 128 + tid] = s1;
      us2[c * 128 + tid] = s2;
    }
  }
}

// ---------------------------------------------------------------------------
// k_prept: tiled transpose of weights to bf16, N-major ([n][k]) so MFMA
// b-fragments are contiguous 16B loads. 128 blocks x 256 threads.
// ---------------------------------------------------------------------------
__global__ void k_prept(const float* __restrict__ Wo, const float* __restrict__ Wk,
                        const float* __restrict__ Wv, const float* __restrict__ W1,
                        uint16_t* __restrict__ WOT, uint16_t* __restrict__ WKVT,
                        uint16_t* __restrict__ W1T)
{
  __shared__ float ts[64][65];
  int tid = threadIdx.x;
  int bid = blockIdx.x;
  const float* src;
  uint16_t* dst;
  int ncols, kt, nt;
  if (bid < 16)      { src = Wo; dst = WOT; ncols = 256; kt = bid >> 2; nt = bid & 3; }
  else if (bid < 32) { int t = bid - 16; src = Wk; dst = WKVT; ncols = 256; kt = t >> 2; nt = t & 3; }
  else if (bid < 48) { int t = bid - 32; src = Wv; dst = WKVT + 256 * 256; ncols = 256; kt = t >> 2; nt = t & 3; }
  else { int t = bid - 48; int c = t >> 3; int tt = t & 7;
         src = W1 + (long)c * 256 * 128; dst = W1T + (long)c * 128 * 256;
         ncols = 128; kt = tt >> 1; nt = tt & 1; }
  for (int idx = tid; idx < 4096; idx += 256) {
    int i = idx >> 6, j = idx & 63;
    ts[i][j] = src[(long)(kt * 64 + i) * ncols + nt * 64 + j];
  }
  __syncthreads();
  for (int idx = tid; idx < 4096; idx += 256) {
    int i = idx >> 6, j = idx & 63;
    dst[(long)(nt * 64 + i) * 256 + kt * 64 + j] = f2bf(ts[j][i]);
  }
}

// ---------------------------------------------------------------------------
// k_ruleq: rule embeddings (sparse multi-hot) + Q projection (f32)
// ---------------------------------------------------------------------------
__global__ void k_ruleq(const float* __restrict__ basic, const float* __restrict__ cruc,
                        const float* __restrict__ Wtb, const float* __restrict__ btb,
                        const float* __restrict__ Wtk, const float* __restrict__ btk,
                        const float* __restrict__ Wq, const float* __restrict__ bq,
                        float* __restrict__ Qout)
{
  __shared__ float row_s[2048];
  __shared__ float rule_s[256];
  __shared__ int   nzi[128];
  __shared__ float nzv[128];
  __shared__ int   nzc;
  int tid = threadIdx.x, r = blockIdx.x;
  float acc = btb[tid] + btk[tid];
  for (int m = 0; m < 2; ++m) {
    const float* src = m ? cruc : basic;
    const float* W   = m ? Wtk : Wtb;
    for (int idx = tid; idx < 2048; idx += 256)
      row_s[idx] = (idx < NV) ? src[r * NV + idx] : 0.0f;
    if (tid == 0) nzc = 0;
    __syncthreads();
    if (tid < 64) {
      int base = 0;
      for (int ch = 0; ch < 32; ++ch) {
        int idx = ch * 64 + tid;
        float v = row_s[idx];
        unsigned long long bm = __ballot(v != 0.0f);
        if (v != 0.0f) {
          int pos = base + (int)__popcll(bm & ((1ull << tid) - 1ull));
          if (pos < 128) { nzi[pos] = idx; nzv[pos] = v; }
        }
        base += (int)__popcll(bm);
      }
      if (tid == 0) nzc = (base > 128) ? 128 : base;
    }
    __syncthreads();
    int n = nzc;
    for (int t = 0; t < n; ++t) acc += nzv[t] * W[nzi[t] * 256 + tid];
    __syncthreads();
  }
  rule_s[tid] = acc;
  __syncthreads();
  float q = bq[tid];
  for (int k2 = 0; k2 < 256; ++k2) q += rule_s[k2] * Wq[k2 * 256 + tid];
  Qout[r * 256 + tid] = q;
}

// ---------------------------------------------------------------------------
// k_kvproj (MFMA): KX/VX = vis @ Wk/Wv + bias. Block = 64 rows x 64 cols.
// ---------------------------------------------------------------------------
__global__ __launch_bounds__(256) void k_kvproj(
    const float* __restrict__ vis, const uint16_t* __restrict__ WKVT,
    const float* __restrict__ bk, const float* __restrict__ bv,
    uint16_t* __restrict__ KX, uint16_t* __restrict__ VX)
{
  __shared__ uint16_t A_s[64 * 264];
  int tid = threadIdx.x;
  int lane = tid & 63, w = tid >> 6;
  int r15 = lane & 15, kg = lane >> 4;
  long m0 = (long)blockIdx.x * 64;
  int n0 = blockIdx.y * 64 + w * 16;
  for (int idx = tid; idx < 2048; idx += 256) {
    int r = idx >> 5, ch = idx & 31;
    const float4* p = (const float4*)&vis[(m0 + r) * 256 + ch * 8];
    float4 v0 = p[0], v1 = p[1];
    uint4 wd;
    wd.x = (uint32_t)f2bf(v0.x) | ((uint32_t)f2bf(v0.y) << 16);
    wd.y = (uint32_t)f2bf(v0.z) | ((uint32_t)f2bf(v0.w) << 16);
    wd.z = (uint32_t)f2bf(v1.x) | ((uint32_t)f2bf(v1.y) << 16);
    wd.w = (uint32_t)f2bf(v1.z) | ((uint32_t)f2bf(v1.w) << 16);
    *(uint4*)&A_s[r * 264 + ch * 8] = wd;
  }
  __syncthreads();
  const uint16_t* bptr = &WKVT[(long)(n0 + r15) * 256 + kg * 8];
  f32x4 acc[4];
  #pragma unroll
  for (int mt = 0; mt < 4; ++mt) acc[mt] = (f32x4){0.f, 0.f, 0.f, 0.f};
  #pragma unroll
  for (int ks = 0; ks < 8; ++ks) {
    bf16x8 bfr = *(const bf16x8*)(bptr + ks * 32);
    #pragma unroll
    for (int mt = 0; mt < 4; ++mt) {
      bf16x8 afr = *(const bf16x8*)&A_s[(mt * 16 + r15) * 264 + kg * 8 + ks * 32];
      acc[mt] = __builtin_amdgcn_mfma_f32_16x16x32_bf16(afr, bfr, acc[mt], 0, 0, 0);
    }
  }
  int col = n0 + r15;
  float bb = (col < 256) ? bk[col] : bv[col - 256];
  uint16_t* outp = (col < 256) ? KX : VX;
  int oc = (col < 256) ? col : col - 256;
  #pragma unroll
  for (int mt = 0; mt < 4; ++mt)
    #pragma unroll
    for (int j = 0; j < 4; ++j) {
      long row = m0 + mt * 16 + kg * 4 + j;
      outp[row * 256 + oc] = f2bf(acc[mt][j] + bb);
    }
}

// ---------------------------------------------------------------------------
// k_attn: one block per batch b, 1024 threads = 256 rules x 4 key-chunks.
// ---------------------------------------------------------------------------
__global__ __launch_bounds__(1024) void k_attn(const float* __restrict__ Q,
                         const uint16_t* __restrict__ KX, const uint16_t* __restrict__ VX,
                         uint16_t* __restrict__ EMB)
{
  __shared__ float K_s[64][65];
  __shared__ float V_s[64][65];
  __shared__ uint16_t Q_s[256 * 66];
  int tid = threadIdx.x;
  int b = blockIdx.x;
  int r = tid >> 2, q = tid & 3;
  for (int h = 0; h < 4; ++h) {
    __syncthreads();
    for (int idx = tid; idx < 4096; idx += 1024) {
      int s = idx >> 6, d = idx & 63;
      long gi = ((long)(b * 64 + s)) * 256 + h * 64 + d;
      K_s[s][d] = bf2f(KX[gi]);
      V_s[s][d] = bf2f(VX[gi]);
    }
    for (int idx = tid; idx < 16384; idx += 1024) {
      int rr = idx >> 6, d = idx & 63;
      Q_s[rr * 66 + d] = f2bf(Q[rr * 256 + h * 64 + d] * 0.125f);
    }
    __syncthreads();
    float att[16];
    #pragma unroll
    for (int k = 0; k < 16; ++k) att[k] = 0.f;
    for (int d = 0; d < 64; ++d) {
      float qd = bf2f(Q_s[r * 66 + d]);
      #pragma unroll
      for (int k = 0; k < 16; ++k) att[k] += qd * K_s[q * 16 + k][d];
    }
    float m = att[0];
    #pragma unroll
    for (int k = 1; k < 16; ++k) m = fmaxf(m, att[k]);
    m = fmaxf(m, __shfl_xor(m, 1));
    m = fmaxf(m, __shfl_xor(m, 2));
    float sum = 0.f;
    #pragma unroll
    for (int k = 0; k < 16; ++k) { att[k] = __expf(att[k] - m); sum += att[k]; }
    sum += __shfl_xor(sum, 1);
    sum += __shfl_xor(sum, 2);
    float rs = 1.0f / sum;
    #pragma unroll
    for (int k = 0; k < 16; ++k) att[k] *= rs;
    long obase = ((long)(b * 256 + r)) * 256 + h * 64;
    #pragma unroll
    for (int j = 0; j < 4; ++j) {
      float op[16];
      #pragma unroll
      for (int d = 0; d < 16; ++d) op[d] = 0.f;
      #pragma unroll
      for (int k = 0; k < 16; ++k) {
        float a = att[k];
        #pragma unroll
        for (int d = 0; d < 16; ++d) op[d] += a * V_s[q * 16 + k][j * 16 + d];
      }
      #pragma unroll
      for (int d = 0; d < 16; ++d) {
        op[d] += __shfl_xor(op[d], 1);
        op[d] += __shfl_xor(op[d], 2);
      }
      if (q == 0) {
        #pragma unroll
        for (int d = 0; d < 16; d += 2) {
          uint32_t pk = (uint32_t)f2bf(op[d]) | ((uint32_t)f2bf(op[d + 1]) << 16);
          *(uint32_t*)(&EMB[obase + j * 16 + d]) = pk;
        }
      }
    }
  }
}

// ---------------------------------------------------------------------------
// k_wo (MFMA): EMB = EMB @ Wo + bo, in place. One block owns a 64-row range,
// stages all 256 cols once, computes 4 col-quadrants internally (race-free).
// ---------------------------------------------------------------------------
__global__ __launch_bounds__(256) void k_wo(uint16_t* __restrict__ EMB,
                    const uint16_t* __restrict__ WOT, const float* __restrict__ bo)
{
  __shared__ uint16_t A_s[64 * 264];
  int tid = threadIdx.x;
  int lane = tid & 63, w = tid >> 6;
  int r15 = lane & 15, kg = lane >> 4;
  long m0 = (long)blockIdx.x * 64;
  for (int idx = tid; idx < 2048; idx += 256) {
    int r = idx >> 5, ch = idx & 31;
    uint4 v = *(const uint4*)&EMB[(m0 + r) * 256 + ch * 8];
    *(uint4*)&A_s[r * 264 + ch * 8] = v;
  }
  __syncthreads();
  #pragma unroll
  for (int nt = 0; nt < 4; ++nt) {
    int n0 = nt * 64 + w * 16;
    const uint16_t* bptr = &WOT[(long)(n0 + r15) * 256 + kg * 8];
    f32x4 acc[4];
    #pragma unroll
    for (int mt = 0; mt < 4; ++mt) acc[mt] = (f32x4){0.f, 0.f, 0.f, 0.f};
    #pragma unroll
    for (int ks = 0; ks < 8; ++ks) {
      bf16x8 bfr = *(const bf16x8*)(bptr + ks * 32);
      #pragma unroll
      for (int mt = 0; mt < 4; ++mt) {
        bf16x8 afr = *(const bf16x8*)&A_s[(mt * 16 + r15) * 264 + kg * 8 + ks * 32];
        acc[mt] = __builtin_amdgcn_mfma_f32_16x16x32_bf16(afr, bfr, acc[mt], 0, 0, 0);
      }
    }
    int col = n0 + r15;
    float bb = bo[col];
    #pragma unroll
    for (int mt = 0; mt < 4; ++mt)
      #pragma unroll
      for (int j = 0; j < 4; ++j) {
        long row = m0 + mt * 16 + kg * 4 + j;
        EMB[row * 256 + col] = f2bf(acc[mt][j] + bb);
      }
  }
}

// ---------------------------------------------------------------------------
// k_gat (fused hw1 + 2x MFMA GAT): per (c,b), 1024 threads / 16 waves.
// P1: stage member emb rows. P2: hW1 = emb@W1[c] via MFMA (wave = (mt, nh)).
// P3: write hW1^T (bf16, stride 72) to LDS + e1d/e1s dots from fragments.
// P5: alpha row per rule from neighbor list (no max-sub, clamp 60),
//     unnormalized bf16; den1 -> rd1. P6: G = alpha @ hwt via MFMA.
// P7: g = relu(G*rd1 + b1) in-reg; e2 dots via shfl. P8/P9: den2 / wj.
// P10: t2 from g regs. P11: svec/lvec/log_softmax.
// ---------------------------------------------------------------------------
__global__ __launch_bounds__(1024) void k_gat(
    const uint16_t* __restrict__ EMB, const uint16_t* __restrict__ W1T,
    const float* __restrict__ a1d, const float* __restrict__ a1s,
    const int* __restrict__ lists, const int* __restrict__ cnt_g,
    const int* __restrict__ deg_g, const uint8_t* __restrict__ nbr_g,
    const int8_t* __restrict__ midx_g,
    const float* __restrict__ b1, const float* __restrict__ ud2_g,
    const float* __restrict__ us2_g, const float* __restrict__ W2,
    const float* __restrict__ b2, const float* __restrict__ Wl,
    const float* __restrict__ bl, float* __restrict__ out)
{
  __shared__ uint16_t sh0[256 * 72];   // A_s (64x264) then alpha_s (256x72)
  __shared__ uint16_t hwt_s[128 * 72]; // hW1^T: [f][jm], stride 72
  __shared__ float e1d_s[256], e1s_s[256], rd1_s[256];
  __shared__ float e2d_s[256], e2s_s[256], rd2_s[256], wj_s[256];
  __shared__ float a1d_s[128], a1s_s[128], b1_s[128], ud2_s[128], us2_s[128];
  __shared__ float tpart[16][128];     // rows 0-3 reused as pd/ps partials
  __shared__ float t_s[128], svec[64], lvec[8];
  __shared__ int   list_s[64];
  int tid = threadIdx.x;
  int lane = tid & 63, w = tid >> 6;
  int r15 = lane & 15, kg = lane >> 4;
  int c = blockIdx.x >> 8, b = blockIdx.x & 255;
  int n = cnt_g[c];
  if (tid < 64) list_s[tid] = lists[c * 64 + tid];
  if (tid < 128) {
    a1d_s[tid] = a1d[c * 128 + tid];
    a1s_s[tid] = a1s[c * 128 + tid];
    b1_s[tid]  = b1[c * 128 + tid];
    ud2_s[tid] = ud2_g[c * 128 + tid];
    us2_s[tid] = us2_g[c * 128 + tid];
  }
  if (tid < 256) { e1d_s[tid] = 0.f; e1s_s[tid] = 0.f; }
  __syncthreads();  // B0
  // P1: stage member emb rows (zeros for jm >= n)
  for (int idx = tid; idx < 2048; idx += 1024) {
    int jm = idx >> 5, ch = idx & 31;
    uint4 v = {0u, 0u, 0u, 0u};
    if (jm < n) v = *(const uint4*)&EMB[((long)b * 256 + list_s[jm]) * 256 + ch * 8];
    *(uint4*)&sh0[jm * 264 + ch * 8] = v;
  }
  __syncthreads();  // B1
  // P2: hW1 MFMA. wave w: m-tile mt = w&3 (rows jm), col-pair nh = w>>2.
  int mt = w & 3, nh = w >> 2;
  int colA = nh * 32 + r15, colB = colA + 16;
  const uint16_t* bptr = &W1T[((long)c * 128 + colA) * 256 + kg * 8];
  f32x4 acc0 = (f32x4){0.f, 0.f, 0.f, 0.f};
  f32x4 acc1 = (f32x4){0.f, 0.f, 0.f, 0.f};
  if (mt * 16 < n) {
    #pragma unroll
    for (int ks = 0; ks < 8; ++ks) {
      bf16x8 b0 = *(const bf16x8*)(bptr + ks * 32);
      bf16x8 b1f = *(const bf16x8*)(bptr + 16 * 256 + ks * 32);
      bf16x8 afr = *(const bf16x8*)&sh0[(mt * 16 + r15) * 264 + kg * 8 + ks * 32];
      acc0 = __builtin_amdgcn_mfma_f32_16x16x32_bf16(afr, b0, acc0, 0, 0, 0);
      acc1 = __builtin_amdgcn_mfma_f32_16x16x32_bf16(afr, b1f, acc1, 0, 0, 0);
    }
  }
  // P3: write hwt (transposed, bf16) + pd/ps fragment dots
  {
    uint2 pA, pB;
    pA.x = (uint32_t)f2bf(acc0[0]) | ((uint32_t)f2bf(acc0[1]) << 16);
    pA.y = (uint32_t)f2bf(acc0[2]) | ((uint32_t)f2bf(acc0[3]) << 16);
    pB.x = (uint32_t)f2bf(acc1[0]) | ((uint32_t)f2bf(acc1[1]) << 16);
    pB.y = (uint32_t)f2bf(acc1[2]) | ((uint32_t)f2bf(acc1[3]) << 16);
    *(uint2*)&hwt_s[colA * 72 + mt * 16 + kg * 4] = pA;
    *(uint2*)&hwt_s[colB * 72 + mt * 16 + kg * 4] = pB;
    float adA = a1d_s[colA], adB = a1d_s[colB];
    float asA = a1s_s[colA], asB = a1s_s[colB];
    #pragma unroll
    for (int j = 0; j < 4; ++j) {
      float pd = acc0[j] * adA + acc1[j] * adB;
      float ps = acc0[j] * asA + acc1[j] * asB;
      pd += __shfl_xor(pd, 1); pd += __shfl_xor(pd, 2);
      pd += __shfl_xor(pd, 4); pd += __shfl_xor(pd, 8);
      ps += __shfl_xor(ps, 1); ps += __shfl_xor(ps, 2);
      ps += __shfl_xor(ps, 4); ps += __shfl_xor(ps, 8);
      if (r15 == 0) {
        int jm = mt * 16 + kg * 4 + j;
        tpart[nh][jm] = pd;        // pd partial
        tpart[nh][jm + 64] = ps;   // ps partial
      }
    }
  }
  __syncthreads();  // B2 (all A_s reads done; tpart pd/ps ready)
  // P4: zero alpha region; fill e1d/e1s for members
  for (int idx = tid; idx < 4608; idx += 1024)
    *(uint2*)&sh0[idx * 4] = (uint2){0u, 0u};
  if (tid < 64 && tid < n) {
    float sd = tpart[0][tid] + tpart[1][tid] + tpart[2][tid] + tpart[3][tid];
    float ss = tpart[0][tid + 64] + tpart[1][tid + 64] + tpart[2][tid + 64] + tpart[3][tid + 64];
    int r = list_s[tid];
    e1d_s[r] = sd;
    e1s_s[r] = ss;
  }
  __syncthreads();  // B3
  // P5: alpha scatter + den1 (thread = (rule r, q) with q striding neighbors)
  int r = tid >> 2, q = tid & 3;
  int dg = deg_g[r];
  {
    float e1dv = e1d_s[r];
    float den = 0.f;
    for (int t = q; t < dg; t += 4) {
      int j = nbr_g[r * 64 + t];
      float e = e1dv + e1s_s[j];
      e = fmaxf(e, 0.2f * e);
      e = fminf(e, 60.f);
      float wv = __expf(e);
      den += wv;
      int mi = midx_g[c * 256 + j];
      if (mi >= 0) sh0[r * 72 + mi] = f2bf(wv);
    }
    den += __shfl_xor(den, 1);
    den += __shfl_xor(den, 2);
    if (q == 0) rd1_s[r] = 1.0f / den;
  }
  __syncthreads();  // B4
  // P6: G = alpha @ hwt via MFMA. wave w -> rules w*16..+15, 8 n-tiles.
  f32x4 g[8];
  #pragma unroll
  for (int nt = 0; nt < 8; ++nt) g[nt] = (f32x4){0.f, 0.f, 0.f, 0.f};
  int kslices = (n > 32) ? 2 : 1;
  for (int ks = 0; ks < kslices; ++ks) {
    bf16x8 afr = *(const bf16x8*)&sh0[(w * 16 + r15) * 72 + ks * 32 + kg * 8];
    #pragma unroll
    for (int nt = 0; nt < 8; ++nt) {
      bf16x8 bfr = *(const bf16x8*)&hwt_s[(nt * 16 + r15) * 72 + ks * 32 + kg * 8];
      g[nt] = __builtin_amdgcn_mfma_f32_16x16x32_bf16(afr, bfr, g[nt], 0, 0, 0);
    }
  }
  // P7: epilogue: g = relu(G*rd1 + b1); e2 dots
  {
    float rd1v[4];
    #pragma unroll
    for (int j = 0; j < 4; ++j) rd1v[j] = rd1_s[w * 16 + kg * 4 + j];
    float ed[4] = {0.f, 0.f, 0.f, 0.f}, es[4] = {0.f, 0.f, 0.f, 0.f};
    #pragma unroll
    for (int nt = 0; nt < 8; ++nt) {
      float uf = ud2_s[nt * 16 + r15], sf = us2_s[nt * 16 + r15];
      float bf = b1_s[nt * 16 + r15];
      #pragma unroll
      for (int j = 0; j < 4; ++j) {
        float gv = fmaxf(g[nt][j] * rd1v[j] + bf, 0.f);
        g[nt][j] = gv;
        ed[j] += gv * uf;
        es[j] += gv * sf;
      }
    }
    #pragma unroll
    for (int j = 0; j < 4; ++j) {
      ed[j] += __shfl_xor(ed[j], 1); ed[j] += __shfl_xor(ed[j], 2);
      ed[j] += __shfl_xor(ed[j], 4); ed[j] += __shfl_xor(ed[j], 8);
      es[j] += __shfl_xor(es[j], 1); es[j] += __shfl_xor(es[j], 2);
      es[j] += __shfl_xor(es[j], 4); es[j] += __shfl_xor(es[j], 8);
      if (r15 == 0) {
        e2d_s[w * 16 + kg * 4 + j] = ed[j];
        e2s_s[w * 16 + kg * 4 + j] = es[j];
      }
    }
  }
  __syncthreads();  // B5
  // P8: den2
  {
    float e2dv = e2d_s[r];
    float den2 = 0.f;
    for (int t = q; t < dg; t += 4) {
      int j = nbr_g[r * 64 + t];
      float e = e2dv + e2s_s[j];
      e = fmaxf(e, 0.2f * e);
      e = fminf(e, 60.f);
      den2 += __expf(e);
    }
    den2 += __shfl_xor(den2, 1);
    den2 += __shfl_xor(den2, 2);
    if (q == 0) rd2_s[r] = 1.0f / den2;
  }
  __syncthreads();  // B6
  // P9: column weights wj[r] = sum_i alpha2[i,r]
  {
    float e2sv = e2s_s[r];
    float wj = 0.f;
    for (int t = q; t < dg; t += 4) {
      int i2 = nbr_g[r * 64 + t];
      float e = e2d_s[i2] + e2sv;
      e = fmaxf(e, 0.2f * e);
      e = fminf(e, 60.f);
      wj += __expf(e) * rd2_s[i2];
    }
    wj += __shfl_xor(wj, 1);
    wj += __shfl_xor(wj, 2);
    if (q == 0) wj_s[r] = wj;
  }
  __syncthreads();  // B7
  // P10: t2[f] = sum_r wj[r]*g[r][f] from live fragments
  {
    float wjv[4];
    #pragma unroll
    for (int j = 0; j < 4; ++j) wjv[j] = wj_s[w * 16 + kg * 4 + j];
    #pragma unroll
    for (int nt = 0; nt < 8; ++nt) {
      float tp = wjv[0] * g[nt][0] + wjv[1] * g[nt][1] + wjv[2] * g[nt][2] + wjv[3] * g[nt][3];
      tp += __shfl_xor(tp, 16);
      tp += __shfl_xor(tp, 32);
      if (kg == 0) tpart[w][nt * 16 + r15] = tp;
    }
  }
  __syncthreads();  // B8
  if (tid < 128) {
    float s = 0.f;
    #pragma unroll
    for (int w2 = 0; w2 < 16; ++w2) s += tpart[w2][tid];
    t_s[tid] = s;
  }
  __syncthreads();
  if (tid < 64) {
    float s = 256.0f * b2[c * 64 + tid];
    for (int f = 0; f < 128; ++f) s += t_s[f] * W2[((long)c * 128 + f) * 64 + tid];
    svec[tid] = s;
  }
  __syncthreads();
  if (tid < 6) {
    float lg = 256.0f * bl[c * 6 + tid];
    for (int f = 0; f < 64; ++f) lg += svec[f] * Wl[((long)c * 64 + f) * 6 + tid];
    lvec[tid] = lg;
  }
  __syncthreads();
  if (tid == 0) {
    float mm = lvec[0];
    for (int k2 = 1; k2 < 6; ++k2) mm = fmaxf(mm, lvec[k2]);
    float ss = 0.f;
    for (int k2 = 0; k2 < 6; ++k2) ss += __expf(lvec[k2] - mm);
    float lse = mm + __logf(ss);
    for (int k2 = 0; k2 < 6; ++k2) out[((long)c * 256 + b) * 6 + k2] = lvec[k2] - lse;
  }
}

// ---------------------------------------------------------------------------
extern "C" void kernel_launch(void* const* d_in, const int* in_sizes, int n_in,
                              void* d_out, int out_size, void* d_ws, size_t ws_size,
                              hipStream_t stream)
{
  const float* vis   = (const float*)d_in[0];
  const float* basic = (const float*)d_in[1];
  const float* cruc  = (const float*)d_in[2];
  const float* Wtb   = (const float*)d_in[3];
  const float* btb   = (const float*)d_in[4];
  const float* Wtk   = (const float*)d_in[5];
  const float* btk   = (const float*)d_in[6];
  const float* Wq    = (const float*)d_in[7];
  const float* bq    = (const float*)d_in[8];
  const float* Wk    = (const float*)d_in[9];
  const float* bk    = (const float*)d_in[10];
  const float* Wv    = (const float*)d_in[11];
  const float* bv    = (const float*)d_in[12];
  const float* Wo    = (const float*)d_in[13];
  const float* bo    = (const float*)d_in[14];
  const float* W1    = (const float*)d_in[15];
  const float* a1s   = (const float*)d_in[16];
  const float* a1d   = (const float*)d_in[17];
  const float* b1    = (const float*)d_in[18];
  const float* W2    = (const float*)d_in[19];
  const float* a2s   = (const float*)d_in[20];
  const float* a2d   = (const float*)d_in[21];
  const float* b2    = (const float*)d_in[22];
  const float* Wl    = (const float*)d_in[23];
  const float* bl    = (const float*)d_in[24];
  const void*  adj   = d_in[25];
  const int*   mask  = (const int*)d_in[26];
  float* out = (float*)d_out;
  char* ws = (char*)d_ws;

  float*    Qw   = (float*)(ws + 0);            // 262144
  uint32_t* ADJ  = (uint32_t*)(ws + 262144);    // 8192
  int*      CLS  = (int*)(ws + 270336);         // 1024
  int*      LST  = (int*)(ws + 271360);         // 2560
  int*      CNT  = (int*)(ws + 273920);         // 64
  int*      DEG  = (int*)(ws + 273984);         // 1024
  uint8_t*  NBR  = (uint8_t*)(ws + 275008);     // 16384
  int8_t*   MIDX = (int8_t*)(ws + 291392);      // 2560
  float*    UD2  = (float*)(ws + 293952);       // 5120
  float*    US2  = (float*)(ws + 299072);       // 5120
  uint16_t* WOT  = (uint16_t*)(ws + 304192);    // 131072
  uint16_t* WKVT = (uint16_t*)(ws + 435264);    // 262144
  uint16_t* W1T  = (uint16_t*)(ws + 697408);    // 655360
  uint16_t* KX   = (uint16_t*)(ws + 1352768);   // 8388608
  uint16_t* VX   = (uint16_t*)(ws + 9741376);   // 8388608
  uint16_t* EMB  = (uint16_t*)(ws + 18129984);  // 33554432 -> total ~49.3 MiB

  hipLaunchKernelGGL(k_prep, dim3(11), dim3(256), 0, stream,
                     adj, mask, W2, a2s, a2d, ADJ, CLS, LST, CNT, DEG, NBR, MIDX, UD2, US2);
  hipLaunchKernelGGL(k_prept, dim3(128), dim3(256), 0, stream,
                     Wo, Wk, Wv, W1, WOT, WKVT, W1T);
  hipLaunchKernelGGL(k_ruleq, dim3(256), dim3(256), 0, stream,
                     basic, cruc, Wtb, btb, Wtk, btk, Wq, bq, Qw);
  hipLaunchKernelGGL(k_kvproj, dim3(256, 8), dim3(256), 0, stream,
                     vis, WKVT, bk, bv, KX, VX);
  hipLaunchKernelGGL(k_attn, dim3(256), dim3(1024), 0, stream, Qw, KX, VX, EMB);
  hipLaunchKernelGGL(k_wo, dim3(1024), dim3(256), 0, stream, EMB, WOT, bo);
  hipLaunchKernelGGL(k_gat, dim3(2560), dim3(1024), 0, stream,
                     EMB, W1T, a1d, a1s, LST, CNT, DEG, NBR, MIDX,
                     b1, UD2, US2, W2, b2, Wl, bl, out);
}

// Round 8
// 478.436 us; speedup vs baseline: 1.4987x; 1.4987x over previous
//
#include <hip/hip_runtime.h>
#include <stdint.h>

// Sizes (fixed by the problem)
#define NB 256
#define NS 64
#define NR 256
#define NV 2000
#define NC 10
#define NK 6
#define ND 256

typedef __attribute__((ext_vector_type(8))) short bf16x8;
typedef __attribute__((ext_vector_type(4))) float f32x4;

__device__ __forceinline__ float bf2f(uint16_t u) {
  return __uint_as_float(((uint32_t)u) << 16);
}
__device__ __forceinline__ uint16_t f2bf(float f) {
  uint32_t x = __float_as_uint(f);
  x += 0x7FFFu + ((x >> 16) & 1u);
  return (uint16_t)(x >> 16);
}

// ---------------------------------------------------------------------------
// k_prep: block 0 = adjacency dtype-detect + bitmask + neighbor lists + class
//         lists + member index; blocks 1..10 = ud2/us2 = W2[c] @ a2{d,s}
// ---------------------------------------------------------------------------
__global__ void k_prep(const void* __restrict__ adj_raw, const int* __restrict__ mask,
                       const float* __restrict__ W2, const float* __restrict__ a2s,
                       const float* __restrict__ a2d,
                       uint32_t* __restrict__ adjbits, int* __restrict__ cls,
                       int* __restrict__ lists, int* __restrict__ cnt,
                       int* __restrict__ deg, uint8_t* __restrict__ nbr,
                       int8_t* __restrict__ midx,
                       float* __restrict__ ud2, float* __restrict__ us2)
{
  int tid = threadIdx.x;
  if (blockIdx.x == 0) {
    __shared__ int s_is4;
    if (tid == 0) s_is4 = 1;
    __syncthreads();
    const uint32_t* u = (const uint32_t*)adj_raw;
    int ok = 1;
    for (int idx = tid; idx < 16384; idx += 256) {
      uint32_t v = u[idx];
      if (!(v == 0u || v == 1u || v == 0x3F800000u)) ok = 0;
    }
    if (!ok) atomicAnd(&s_is4, 0);
    __syncthreads();
    int is4 = s_is4;
    const uint8_t* b8 = (const uint8_t*)adj_raw;
    int dg = 0;
    for (int w = 0; w < 8; ++w) {
      uint32_t word = 0;
      for (int jb = 0; jb < 32; ++jb) {
        int j = w * 32 + jb;
        int bit = is4 ? (u[tid * 256 + j] != 0u) : (b8[tid * 256 + j] != 0);
        if (bit) {
          word |= (1u << jb);
          if (dg < 64) nbr[tid * 64 + dg] = (uint8_t)j;
          dg++;
        }
      }
      adjbits[tid * 8 + w] = word;
    }
    deg[tid] = (dg > 64) ? 64 : dg;
    int c = 0;
    for (int cc = 0; cc < NC; ++cc) if (mask[cc * 256 + tid] != 0) c = cc;
    cls[tid] = c;
    __syncthreads();
    if (tid == 0) {
      int cn[NC];
      for (int i = 0; i < NC; ++i) cn[i] = 0;
      for (int r = 0; r < 256; ++r) {
        int cc = cls[r];
        if (cn[cc] < 64) lists[cc * 64 + cn[cc]] = r;
        cn[cc]++;
      }
      for (int i = 0; i < NC; ++i) cnt[i] = (cn[i] > 64) ? 64 : cn[i];
      for (int i = 0; i < NC * 256; ++i) midx[i] = -1;
      for (int cc = 0; cc < NC; ++cc)
        for (int i = 0; i < cnt[cc]; ++i)
          midx[cc * 256 + lists[cc * 64 + i]] = (int8_t)i;
    }
  } else {
    int c = blockIdx.x - 1;
    if (tid < 128) {
      float s1 = 0.f, s2 = 0.f;
      for (int g = 0; g < 64; ++g) {
        float w = W2[(c * 128 + tid) * 64 + g];
        s1 += w * a2d[c * 64 + g];
        s2 += w * a2s[c * 64 + g];
      }
      ud2[c * 128 + tid] = s1;
      us2[c * 128 + tid] = s2;
    }
  }
}

// ---------------------------------------------------------------------------
// k_prept: tiled transpose of weights to bf16, N-major ([n][k]) so MFMA
// b-fragments are contiguous 16B loads. 128 blocks x 256 threads.
// ---------------------------------------------------------------------------
__global__ void k_prept(const float* __restrict__ Wo, const float* __restrict__ Wk,
                        const float* __restrict__ Wv, const float* __restrict__ W1,
                        uint16_t* __restrict__ WOT, uint16_t* __restrict__ WKVT,
                        uint16_t* __restrict__ W1T)
{
  __shared__ float ts[64][65];
  int tid = threadIdx.x;
  int bid = blockIdx.x;
  const float* src;
  uint16_t* dst;
  int ncols, kt, nt;
  if (bid < 16)      { src = Wo; dst = WOT; ncols = 256; kt = bid >> 2; nt = bid & 3; }
  else if (bid < 32) { int t = bid - 16; src = Wk; dst = WKVT; ncols = 256; kt = t >> 2; nt = t & 3; }
  else if (bid < 48) { int t = bid - 32; src = Wv; dst = WKVT + 256 * 256; ncols = 256; kt = t >> 2; nt = t & 3; }
  else { int t = bid - 48; int c = t >> 3; int tt = t & 7;
         src = W1 + (long)c * 256 * 128; dst = W1T + (long)c * 128 * 256;
         ncols = 128; kt = tt >> 1; nt = tt & 1; }
  for (int idx = tid; idx < 4096; idx += 256) {
    int i = idx >> 6, j = idx & 63;
    ts[i][j] = src[(long)(kt * 64 + i) * ncols + nt * 64 + j];
  }
  __syncthreads();
  for (int idx = tid; idx < 4096; idx += 256) {
    int i = idx >> 6, j = idx & 63;
    dst[(long)(nt * 64 + i) * 256 + kt * 64 + j] = f2bf(ts[j][i]);
  }
}

// ---------------------------------------------------------------------------
// k_ruleq: rule embeddings (sparse multi-hot) + Q projection. Writes Q as
// bf16 pre-scaled by 1/8 (the attention scale) for direct MFMA a-frag use.
// ---------------------------------------------------------------------------
__global__ void k_ruleq(const float* __restrict__ basic, const float* __restrict__ cruc,
                        const float* __restrict__ Wtb, const float* __restrict__ btb,
                        const float* __restrict__ Wtk, const float* __restrict__ btk,
                        const float* __restrict__ Wq, const float* __restrict__ bq,
                        uint16_t* __restrict__ Qbf)
{
  __shared__ float row_s[2048];
  __shared__ float rule_s[256];
  __shared__ int   nzi[128];
  __shared__ float nzv[128];
  __shared__ int   nzc;
  int tid = threadIdx.x, r = blockIdx.x;
  float acc = btb[tid] + btk[tid];
  for (int m = 0; m < 2; ++m) {
    const float* src = m ? cruc : basic;
    const float* W   = m ? Wtk : Wtb;
    for (int idx = tid; idx < 2048; idx += 256)
      row_s[idx] = (idx < NV) ? src[r * NV + idx] : 0.0f;
    if (tid == 0) nzc = 0;
    __syncthreads();
    if (tid < 64) {
      int base = 0;
      for (int ch = 0; ch < 32; ++ch) {
        int idx = ch * 64 + tid;
        float v = row_s[idx];
        unsigned long long bm = __ballot(v != 0.0f);
        if (v != 0.0f) {
          int pos = base + (int)__popcll(bm & ((1ull << tid) - 1ull));
          if (pos < 128) { nzi[pos] = idx; nzv[pos] = v; }
        }
        base += (int)__popcll(bm);
      }
      if (tid == 0) nzc = (base > 128) ? 128 : base;
    }
    __syncthreads();
    int n = nzc;
    for (int t = 0; t < n; ++t) acc += nzv[t] * W[nzi[t] * 256 + tid];
    __syncthreads();
  }
  rule_s[tid] = acc;
  __syncthreads();
  float q = bq[tid];
  for (int k2 = 0; k2 < 256; ++k2) q += rule_s[k2] * Wq[k2 * 256 + tid];
  Qbf[r * 256 + tid] = f2bf(q * 0.125f);
}

// ---------------------------------------------------------------------------
// k_kvproj (MFMA): KX/VX = vis @ Wk/Wv + bias. Block = 64 rows x 64 cols.
// ---------------------------------------------------------------------------
__global__ __launch_bounds__(256) void k_kvproj(
    const float* __restrict__ vis, const uint16_t* __restrict__ WKVT,
    const float* __restrict__ bk, const float* __restrict__ bv,
    uint16_t* __restrict__ KX, uint16_t* __restrict__ VX)
{
  __shared__ uint16_t A_s[64 * 264];
  int tid = threadIdx.x;
  int lane = tid & 63, w = tid >> 6;
  int r15 = lane & 15, kg = lane >> 4;
  long m0 = (long)blockIdx.x * 64;
  int n0 = blockIdx.y * 64 + w * 16;
  for (int idx = tid; idx < 2048; idx += 256) {
    int r = idx >> 5, ch = idx & 31;
    const float4* p = (const float4*)&vis[(m0 + r) * 256 + ch * 8];
    float4 v0 = p[0], v1 = p[1];
    uint4 wd;
    wd.x = (uint32_t)f2bf(v0.x) | ((uint32_t)f2bf(v0.y) << 16);
    wd.y = (uint32_t)f2bf(v0.z) | ((uint32_t)f2bf(v0.w) << 16);
    wd.z = (uint32_t)f2bf(v1.x) | ((uint32_t)f2bf(v1.y) << 16);
    wd.w = (uint32_t)f2bf(v1.z) | ((uint32_t)f2bf(v1.w) << 16);
    *(uint4*)&A_s[r * 264 + ch * 8] = wd;
  }
  __syncthreads();
  const uint16_t* bptr = &WKVT[(long)(n0 + r15) * 256 + kg * 8];
  f32x4 acc[4];
  #pragma unroll
  for (int mt = 0; mt < 4; ++mt) acc[mt] = (f32x4){0.f, 0.f, 0.f, 0.f};
  #pragma unroll
  for (int ks = 0; ks < 8; ++ks) {
    bf16x8 bfr = *(const bf16x8*)(bptr + ks * 32);
    #pragma unroll
    for (int mt = 0; mt < 4; ++mt) {
      bf16x8 afr = *(const bf16x8*)&A_s[(mt * 16 + r15) * 264 + kg * 8 + ks * 32];
      acc[mt] = __builtin_amdgcn_mfma_f32_16x16x32_bf16(afr, bfr, acc[mt], 0, 0, 0);
    }
  }
  int col = n0 + r15;
  float bb = (col < 256) ? bk[col] : bv[col - 256];
  uint16_t* outp = (col < 256) ? KX : VX;
  int oc = (col < 256) ? col : col - 256;
  #pragma unroll
  for (int mt = 0; mt < 4; ++mt)
    #pragma unroll
    for (int j = 0; j < 4; ++j) {
      long row = m0 + mt * 16 + kg * 4 + j;
      outp[row * 256 + oc] = f2bf(acc[mt][j] + bb);
    }
}

// ---------------------------------------------------------------------------
// k_attn (MFMA): block = (batch b, half of rules), 512 thr / 8 waves.
// Per head: S = Qbf @ KX^T via MFMA with BOTH operands read directly from
// global (both are d-contiguous); in-register softmax (shfl_xor over the 16
// col-lanes); P -> LDS [r][72] bf16 (2-way bank alias = free); V^T staged
// [d][72]; PV via MFMA; scalar bf16 writes to EMB.
// ---------------------------------------------------------------------------
__global__ __launch_bounds__(512) void k_attn(const uint16_t* __restrict__ Qbf,
                         const uint16_t* __restrict__ KX, const uint16_t* __restrict__ VX,
                         uint16_t* __restrict__ EMB)
{
  __shared__ uint16_t p_s[128 * 72];
  __shared__ uint16_t vt_s[64 * 72];
  int tid = threadIdx.x;
  int lane = tid & 63, w = tid >> 6;   // 8 waves
  int r15 = lane & 15, kg = lane >> 4;
  int b = blockIdx.x >> 1;
  int rbase = (blockIdx.x & 1) * 128;
  for (int h = 0; h < 4; ++h) {
    __syncthreads();  // prev head's vt_s reads done
    // stage V^T: vt_s[d][s]
    for (int idx = tid; idx < 2048; idx += 512) {
      int s = idx >> 5, d2 = (idx & 31) * 2;
      uint32_t v = *(const uint32_t*)&VX[((long)(b * 64 + s)) * 256 + h * 64 + d2];
      vt_s[d2 * 72 + s] = (uint16_t)(v & 0xffff);
      vt_s[(d2 + 1) * 72 + s] = (uint16_t)(v >> 16);
    }
    __syncthreads();
    // S = Q K^T : wave w owns rules rbase + w*16 .. +15; 4 n-tiles of s.
    f32x4 sacc[4];
    #pragma unroll
    for (int nt = 0; nt < 4; ++nt) sacc[nt] = (f32x4){0.f, 0.f, 0.f, 0.f};
    #pragma unroll
    for (int ks = 0; ks < 2; ++ks) {
      bf16x8 afr = *(const bf16x8*)&Qbf[(long)(rbase + w * 16 + r15) * 256 + h * 64 + ks * 32 + kg * 8];
      #pragma unroll
      for (int nt = 0; nt < 4; ++nt) {
        bf16x8 bfr = *(const bf16x8*)&KX[((long)(b * 64 + nt * 16 + r15)) * 256 + h * 64 + ks * 32 + kg * 8];
        sacc[nt] = __builtin_amdgcn_mfma_f32_16x16x32_bf16(afr, bfr, sacc[nt], 0, 0, 0);
      }
    }
    // softmax over s: row (w*16 + kg*4 + j), cols nt*16 + r15
    #pragma unroll
    for (int j = 0; j < 4; ++j) {
      float m = sacc[0][j];
      #pragma unroll
      for (int nt = 1; nt < 4; ++nt) m = fmaxf(m, sacc[nt][j]);
      m = fmaxf(m, __shfl_xor(m, 1));
      m = fmaxf(m, __shfl_xor(m, 2));
      m = fmaxf(m, __shfl_xor(m, 4));
      m = fmaxf(m, __shfl_xor(m, 8));
      float pv[4];
      float sum = 0.f;
      #pragma unroll
      for (int nt = 0; nt < 4; ++nt) { pv[nt] = __expf(sacc[nt][j] - m); sum += pv[nt]; }
      sum += __shfl_xor(sum, 1);
      sum += __shfl_xor(sum, 2);
      sum += __shfl_xor(sum, 4);
      sum += __shfl_xor(sum, 8);
      float rs = 1.0f / sum;
      #pragma unroll
      for (int nt = 0; nt < 4; ++nt)
        p_s[(w * 16 + kg * 4 + j) * 72 + nt * 16 + r15] = f2bf(pv[nt] * rs);
    }
    // PV: out[r][d] = P[r][s] V[s][d]; b-frag from vt_s (B[n=d][k=s])
    f32x4 oacc[4];
    #pragma unroll
    for (int nt = 0; nt < 4; ++nt) oacc[nt] = (f32x4){0.f, 0.f, 0.f, 0.f};
    #pragma unroll
    for (int ks = 0; ks < 2; ++ks) {
      bf16x8 afr = *(const bf16x8*)&p_s[(w * 16 + r15) * 72 + ks * 32 + kg * 8];
      #pragma unroll
      for (int nt = 0; nt < 4; ++nt) {
        bf16x8 bfr = *(const bf16x8*)&vt_s[(nt * 16 + r15) * 72 + ks * 32 + kg * 8];
        oacc[nt] = __builtin_amdgcn_mfma_f32_16x16x32_bf16(afr, bfr, oacc[nt], 0, 0, 0);
      }
    }
    #pragma unroll
    for (int nt = 0; nt < 4; ++nt)
      #pragma unroll
      for (int j = 0; j < 4; ++j) {
        long row = (long)(b * 256 + rbase + w * 16 + kg * 4 + j);
        EMB[row * 256 + h * 64 + nt * 16 + r15] = f2bf(oacc[nt][j]);
      }
  }
}

// ---------------------------------------------------------------------------
// k_wo (MFMA): EMB = EMB @ Wo + bo, in place. One block owns a 64-row range,
// stages all 256 cols once, computes 4 col-quadrants internally (race-free).
// ---------------------------------------------------------------------------
__global__ __launch_bounds__(256) void k_wo(uint16_t* __restrict__ EMB,
                    const uint16_t* __restrict__ WOT, const float* __restrict__ bo)
{
  __shared__ uint16_t A_s[64 * 264];
  int tid = threadIdx.x;
  int lane = tid & 63, w = tid >> 6;
  int r15 = lane & 15, kg = lane >> 4;
  long m0 = (long)blockIdx.x * 64;
  for (int idx = tid; idx < 2048; idx += 256) {
    int r = idx >> 5, ch = idx & 31;
    uint4 v = *(const uint4*)&EMB[(m0 + r) * 256 + ch * 8];
    *(uint4*)&A_s[r * 264 + ch * 8] = v;
  }
  __syncthreads();
  #pragma unroll
  for (int nt = 0; nt < 4; ++nt) {
    int n0 = nt * 64 + w * 16;
    const uint16_t* bptr = &WOT[(long)(n0 + r15) * 256 + kg * 8];
    f32x4 acc[4];
    #pragma unroll
    for (int mt = 0; mt < 4; ++mt) acc[mt] = (f32x4){0.f, 0.f, 0.f, 0.f};
    #pragma unroll
    for (int ks = 0; ks < 8; ++ks) {
      bf16x8 bfr = *(const bf16x8*)(bptr + ks * 32);
      #pragma unroll
      for (int mt = 0; mt < 4; ++mt) {
        bf16x8 afr = *(const bf16x8*)&A_s[(mt * 16 + r15) * 264 + kg * 8 + ks * 32];
        acc[mt] = __builtin_amdgcn_mfma_f32_16x16x32_bf16(afr, bfr, acc[mt], 0, 0, 0);
      }
    }
    int col = n0 + r15;
    float bb = bo[col];
    #pragma unroll
    for (int mt = 0; mt < 4; ++mt)
      #pragma unroll
      for (int j = 0; j < 4; ++j) {
        long row = m0 + mt * 16 + kg * 4 + j;
        EMB[row * 256 + col] = f2bf(acc[mt][j] + bb);
      }
  }
}

// ---------------------------------------------------------------------------
// k_gat (fused hw1 + 2x MFMA GAT): per (c,b), 1024 threads / 16 waves.
// ---------------------------------------------------------------------------
__global__ __launch_bounds__(1024) void k_gat(
    const uint16_t* __restrict__ EMB, const uint16_t* __restrict__ W1T,
    const float* __restrict__ a1d, const float* __restrict__ a1s,
    const int* __restrict__ lists, const int* __restrict__ cnt_g,
    const int* __restrict__ deg_g, const uint8_t* __restrict__ nbr_g,
    const int8_t* __restrict__ midx_g,
    const float* __restrict__ b1, const float* __restrict__ ud2_g,
    const float* __restrict__ us2_g, const float* __restrict__ W2,
    const float* __restrict__ b2, const float* __restrict__ Wl,
    const float* __restrict__ bl, float* __restrict__ out)
{
  __shared__ uint16_t sh0[256 * 72];   // A_s (64x264) then alpha_s (256x72)
  __shared__ uint16_t hwt_s[128 * 72]; // hW1^T: [f][jm], stride 72
  __shared__ float e1d_s[256], e1s_s[256], rd1_s[256];
  __shared__ float e2d_s[256], e2s_s[256], rd2_s[256], wj_s[256];
  __shared__ float a1d_s[128], a1s_s[128], b1_s[128], ud2_s[128], us2_s[128];
  __shared__ float tpart[16][128];
  __shared__ float t_s[128], svec[64], lvec[8];
  __shared__ int   list_s[64];
  int tid = threadIdx.x;
  int lane = tid & 63, w = tid >> 6;
  int r15 = lane & 15, kg = lane >> 4;
  int c = blockIdx.x >> 8, b = blockIdx.x & 255;
  int n = cnt_g[c];
  if (tid < 64) list_s[tid] = lists[c * 64 + tid];
  if (tid < 128) {
    a1d_s[tid] = a1d[c * 128 + tid];
    a1s_s[tid] = a1s[c * 128 + tid];
    b1_s[tid]  = b1[c * 128 + tid];
    ud2_s[tid] = ud2_g[c * 128 + tid];
    us2_s[tid] = us2_g[c * 128 + tid];
  }
  if (tid < 256) { e1d_s[tid] = 0.f; e1s_s[tid] = 0.f; }
  __syncthreads();  // B0
  for (int idx = tid; idx < 2048; idx += 1024) {
    int jm = idx >> 5, ch = idx & 31;
    uint4 v = {0u, 0u, 0u, 0u};
    if (jm < n) v = *(const uint4*)&EMB[((long)b * 256 + list_s[jm]) * 256 + ch * 8];
    *(uint4*)&sh0[jm * 264 + ch * 8] = v;
  }
  __syncthreads();  // B1
  int mt = w & 3, nh = w >> 2;
  int colA = nh * 32 + r15, colB = colA + 16;
  const uint16_t* bptr = &W1T[((long)c * 128 + colA) * 256 + kg * 8];
  f32x4 acc0 = (f32x4){0.f, 0.f, 0.f, 0.f};
  f32x4 acc1 = (f32x4){0.f, 0.f, 0.f, 0.f};
  if (mt * 16 < n) {
    #pragma unroll
    for (int ks = 0; ks < 8; ++ks) {
      bf16x8 b0 = *(const bf16x8*)(bptr + ks * 32);
      bf16x8 b1f = *(const bf16x8*)(bptr + 16 * 256 + ks * 32);
      bf16x8 afr = *(const bf16x8*)&sh0[(mt * 16 + r15) * 264 + kg * 8 + ks * 32];
      acc0 = __builtin_amdgcn_mfma_f32_16x16x32_bf16(afr, b0, acc0, 0, 0, 0);
      acc1 = __builtin_amdgcn_mfma_f32_16x16x32_bf16(afr, b1f, acc1, 0, 0, 0);
    }
  }
  {
    uint2 pA, pB;
    pA.x = (uint32_t)f2bf(acc0[0]) | ((uint32_t)f2bf(acc0[1]) << 16);
    pA.y = (uint32_t)f2bf(acc0[2]) | ((uint32_t)f2bf(acc0[3]) << 16);
    pB.x = (uint32_t)f2bf(acc1[0]) | ((uint32_t)f2bf(acc1[1]) << 16);
    pB.y = (uint32_t)f2bf(acc1[2]) | ((uint32_t)f2bf(acc1[3]) << 16);
    *(uint2*)&hwt_s[colA * 72 + mt * 16 + kg * 4] = pA;
    *(uint2*)&hwt_s[colB * 72 + mt * 16 + kg * 4] = pB;
    float adA = a1d_s[colA], adB = a1d_s[colB];
    float asA = a1s_s[colA], asB = a1s_s[colB];
    #pragma unroll
    for (int j = 0; j < 4; ++j) {
      float pd = acc0[j] * adA + acc1[j] * adB;
      float ps = acc0[j] * asA + acc1[j] * asB;
      pd += __shfl_xor(pd, 1); pd += __shfl_xor(pd, 2);
      pd += __shfl_xor(pd, 4); pd += __shfl_xor(pd, 8);
      ps += __shfl_xor(ps, 1); ps += __shfl_xor(ps, 2);
      ps += __shfl_xor(ps, 4); ps += __shfl_xor(ps, 8);
      if (r15 == 0) {
        int jm = mt * 16 + kg * 4 + j;
        tpart[nh][jm] = pd;
        tpart[nh][jm + 64] = ps;
      }
    }
  }
  __syncthreads();  // B2
  for (int idx = tid; idx < 4608; idx += 1024)
    *(uint2*)&sh0[idx * 4] = (uint2){0u, 0u};
  if (tid < 64 && tid < n) {
    float sd = tpart[0][tid] + tpart[1][tid] + tpart[2][tid] + tpart[3][tid];
    float ss = tpart[0][tid + 64] + tpart[1][tid + 64] + tpart[2][tid + 64] + tpart[3][tid + 64];
    int r = list_s[tid];
    e1d_s[r] = sd;
    e1s_s[r] = ss;
  }
  __syncthreads();  // B3
  int r = tid >> 2, q = tid & 3;
  int dg = deg_g[r];
  {
    float e1dv = e1d_s[r];
    float den = 0.f;
    for (int t = q; t < dg; t += 4) {
      int j = nbr_g[r * 64 + t];
      float e = e1dv + e1s_s[j];
      e = fmaxf(e, 0.2f * e);
      e = fminf(e, 60.f);
      float wv = __expf(e);
      den += wv;
      int mi = midx_g[c * 256 + j];
      if (mi >= 0) sh0[r * 72 + mi] = f2bf(wv);
    }
    den += __shfl_xor(den, 1);
    den += __shfl_xor(den, 2);
    if (q == 0) rd1_s[r] = 1.0f / den;
  }
  __syncthreads();  // B4
  f32x4 g[8];
  #pragma unroll
  for (int nt = 0; nt < 8; ++nt) g[nt] = (f32x4){0.f, 0.f, 0.f, 0.f};
  int kslices = (n > 32) ? 2 : 1;
  for (int ks = 0; ks < kslices; ++ks) {
    bf16x8 afr = *(const bf16x8*)&sh0[(w * 16 + r15) * 72 + ks * 32 + kg * 8];
    #pragma unroll
    for (int nt = 0; nt < 8; ++nt) {
      bf16x8 bfr = *(const bf16x8*)&hwt_s[(nt * 16 + r15) * 72 + ks * 32 + kg * 8];
      g[nt] = __builtin_amdgcn_mfma_f32_16x16x32_bf16(afr, bfr, g[nt], 0, 0, 0);
    }
  }
  {
    float rd1v[4];
    #pragma unroll
    for (int j = 0; j < 4; ++j) rd1v[j] = rd1_s[w * 16 + kg * 4 + j];
    float ed[4] = {0.f, 0.f, 0.f, 0.f}, es[4] = {0.f, 0.f, 0.f, 0.f};
    #pragma unroll
    for (int nt = 0; nt < 8; ++nt) {
      float uf = ud2_s[nt * 16 + r15], sf = us2_s[nt * 16 + r15];
      float bf = b1_s[nt * 16 + r15];
      #pragma unroll
      for (int j = 0; j < 4; ++j) {
        float gv = fmaxf(g[nt][j] * rd1v[j] + bf, 0.f);
        g[nt][j] = gv;
        ed[j] += gv * uf;
        es[j] += gv * sf;
      }
    }
    #pragma unroll
    for (int j = 0; j < 4; ++j) {
      ed[j] += __shfl_xor(ed[j], 1); ed[j] += __shfl_xor(ed[j], 2);
      ed[j] += __shfl_xor(ed[j], 4); ed[j] += __shfl_xor(ed[j], 8);
      es[j] += __shfl_xor(es[j], 1); es[j] += __shfl_xor(es[j], 2);
      es[j] += __shfl_xor(es[j], 4); es[j] += __shfl_xor(es[j], 8);
      if (r15 == 0) {
        e2d_s[w * 16 + kg * 4 + j] = ed[j];
        e2s_s[w * 16 + kg * 4 + j] = es[j];
      }
    }
  }
  __syncthreads();  // B5
  {
    float e2dv = e2d_s[r];
    float den2 = 0.f;
    for (int t = q; t < dg; t += 4) {
      int j = nbr_g[r * 64 + t];
      float e = e2dv + e2s_s[j];
      e = fmaxf(e, 0.2f * e);
      e = fminf(e, 60.f);
      den2 += __expf(e);
    }
    den2 += __shfl_xor(den2, 1);
    den2 += __shfl_xor(den2, 2);
    if (q == 0) rd2_s[r] = 1.0f / den2;
  }
  __syncthreads();  // B6
  {
    float e2sv = e2s_s[r];
    float wj = 0.f;
    for (int t = q; t < dg; t += 4) {
      int i2 = nbr_g[r * 64 + t];
      float e = e2d_s[i2] + e2sv;
      e = fmaxf(e, 0.2f * e);
      e = fminf(e, 60.f);
      wj += __expf(e) * rd2_s[i2];
    }
    wj += __shfl_xor(wj, 1);
    wj += __shfl_xor(wj, 2);
    if (q == 0) wj_s[r] = wj;
  }
  __syncthreads();  // B7
  {
    float wjv[4];
    #pragma unroll
    for (int j = 0; j < 4; ++j) wjv[j] = wj_s[w * 16 + kg * 4 + j];
    #pragma unroll
    for (int nt = 0; nt < 8; ++nt) {
      float tp = wjv[0] * g[nt][0] + wjv[1] * g[nt][1] + wjv[2] * g[nt][2] + wjv[3] * g[nt][3];
      tp += __shfl_xor(tp, 16);
      tp += __shfl_xor(tp, 32);
      if (kg == 0) tpart[w][nt * 16 + r15] = tp;
    }
  }
  __syncthreads();  // B8
  if (tid < 128) {
    float s = 0.f;
    #pragma unroll
    for (int w2 = 0; w2 < 16; ++w2) s += tpart[w2][tid];
    t_s[tid] = s;
  }
  __syncthreads();
  if (tid < 64) {
    float s = 256.0f * b2[c * 64 + tid];
    for (int f = 0; f < 128; ++f) s += t_s[f] * W2[((long)c * 128 + f) * 64 + tid];
    svec[tid] = s;
  }
  __syncthreads();
  if (tid < 6) {
    float lg = 256.0f * bl[c * 6 + tid];
    for (int f = 0; f < 64; ++f) lg += svec[f] * Wl[((long)c * 64 + f) * 6 + tid];
    lvec[tid] = lg;
  }
  __syncthreads();
  if (tid == 0) {
    float mm = lvec[0];
    for (int k2 = 1; k2 < 6; ++k2) mm = fmaxf(mm, lvec[k2]);
    float ss = 0.f;
    for (int k2 = 0; k2 < 6; ++k2) ss += __expf(lvec[k2] - mm);
    float lse = mm + __logf(ss);
    for (int k2 = 0; k2 < 6; ++k2) out[((long)c * 256 + b) * 6 + k2] = lvec[k2] - lse;
  }
}

// ---------------------------------------------------------------------------
extern "C" void kernel_launch(void* const* d_in, const int* in_sizes, int n_in,
                              void* d_out, int out_size, void* d_ws, size_t ws_size,
                              hipStream_t stream)
{
  const float* vis   = (const float*)d_in[0];
  const float* basic = (const float*)d_in[1];
  const float* cruc  = (const float*)d_in[2];
  const float* Wtb   = (const float*)d_in[3];
  const float* btb   = (const float*)d_in[4];
  const float* Wtk   = (const float*)d_in[5];
  const float* btk   = (const float*)d_in[6];
  const float* Wq    = (const float*)d_in[7];
  const float* bq    = (const float*)d_in[8];
  const float* Wk    = (const float*)d_in[9];
  const float* bk    = (const float*)d_in[10];
  const float* Wv    = (const float*)d_in[11];
  const float* bv    = (const float*)d_in[12];
  const float* Wo    = (const float*)d_in[13];
  const float* bo    = (const float*)d_in[14];
  const float* W1    = (const float*)d_in[15];
  const float* a1s   = (const float*)d_in[16];
  const float* a1d   = (const float*)d_in[17];
  const float* b1    = (const float*)d_in[18];
  const float* W2    = (const float*)d_in[19];
  const float* a2s   = (const float*)d_in[20];
  const float* a2d   = (const float*)d_in[21];
  const float* b2    = (const float*)d_in[22];
  const float* Wl    = (const float*)d_in[23];
  const float* bl    = (const float*)d_in[24];
  const void*  adj   = d_in[25];
  const int*   mask  = (const int*)d_in[26];
  float* out = (float*)d_out;
  char* ws = (char*)d_ws;

  uint16_t* QBF  = (uint16_t*)(ws + 0);         // 131072
  uint32_t* ADJ  = (uint32_t*)(ws + 262144);    // 8192
  int*      CLS  = (int*)(ws + 270336);         // 1024
  int*      LST  = (int*)(ws + 271360);         // 2560
  int*      CNT  = (int*)(ws + 273920);         // 64
  int*      DEG  = (int*)(ws + 273984);         // 1024
  uint8_t*  NBR  = (uint8_t*)(ws + 275008);     // 16384
  int8_t*   MIDX = (int8_t*)(ws + 291392);      // 2560
  float*    UD2  = (float*)(ws + 293952);       // 5120
  float*    US2  = (float*)(ws + 299072);       // 5120
  uint16_t* WOT  = (uint16_t*)(ws + 304192);    // 131072
  uint16_t* WKVT = (uint16_t*)(ws + 435264);    // 262144
  uint16_t* W1T  = (uint16_t*)(ws + 697408);    // 655360
  uint16_t* KX   = (uint16_t*)(ws + 1352768);   // 8388608
  uint16_t* VX   = (uint16_t*)(ws + 9741376);   // 8388608
  uint16_t* EMB  = (uint16_t*)(ws + 18129984);  // 33554432 -> total ~49.3 MiB

  hipLaunchKernelGGL(k_prep, dim3(11), dim3(256), 0, stream,
                     adj, mask, W2, a2s, a2d, ADJ, CLS, LST, CNT, DEG, NBR, MIDX, UD2, US2);
  hipLaunchKernelGGL(k_prept, dim3(128), dim3(256), 0, stream,
                     Wo, Wk, Wv, W1, WOT, WKVT, W1T);
  hipLaunchKernelGGL(k_ruleq, dim3(256), dim3(256), 0, stream,
                     basic, cruc, Wtb, btb, Wtk, btk, Wq, bq, QBF);
  hipLaunchKernelGGL(k_kvproj, dim3(256, 8), dim3(256), 0, stream,
                     vis, WKVT, bk, bv, KX, VX);
  hipLaunchKernelGGL(k_attn, dim3(512), dim3(512), 0, stream, QBF, KX, VX, EMB);
  hipLaunchKernelGGL(k_wo, dim3(1024), dim3(256), 0, stream, EMB, WOT, bo);
  hipLaunchKernelGGL(k_gat, dim3(2560), dim3(1024), 0, stream,
                     EMB, W1T, a1d, a1s, LST, CNT, DEG, NBR, MIDX,
                     b1, UD2, US2, W2, b2, Wl, bl, out);
}

// Round 9
// 446.836 us; speedup vs baseline: 1.6047x; 1.0707x over previous
//
#include <hip/hip_runtime.h>
#include <stdint.h>

// Sizes (fixed by the problem)
#define NB 256
#define NS 64
#define NR 256
#define NV 2000
#define NC 10
#define NK 6
#define ND 256

typedef __attribute__((ext_vector_type(8))) short bf16x8;
typedef __attribute__((ext_vector_type(4))) float f32x4;

__device__ __forceinline__ float bf2f(uint16_t u) {
  return __uint_as_float(((uint32_t)u) << 16);
}
__device__ __forceinline__ uint16_t f2bf(float f) {
  uint32_t x = __float_as_uint(f);
  x += 0x7FFFu + ((x >> 16) & 1u);
  return (uint16_t)(x >> 16);
}

// ---------------------------------------------------------------------------
// k_prep: block 0 = adjacency dtype-detect + bitmask + neighbor lists + class
//         lists + member index; blocks 1..10 = ud2/us2 = W2[c] @ a2{d,s}
// ---------------------------------------------------------------------------
__global__ void k_prep(const void* __restrict__ adj_raw, const int* __restrict__ mask,
                       const float* __restrict__ W2, const float* __restrict__ a2s,
                       const float* __restrict__ a2d,
                       uint32_t* __restrict__ adjbits, int* __restrict__ cls,
                       int* __restrict__ lists, int* __restrict__ cnt,
                       int* __restrict__ deg, uint8_t* __restrict__ nbr,
                       int8_t* __restrict__ midx,
                       float* __restrict__ ud2, float* __restrict__ us2)
{
  int tid = threadIdx.x;
  if (blockIdx.x == 0) {
    __shared__ int s_is4;
    if (tid == 0) s_is4 = 1;
    __syncthreads();
    const uint32_t* u = (const uint32_t*)adj_raw;
    int ok = 1;
    for (int idx = tid; idx < 16384; idx += 256) {
      uint32_t v = u[idx];
      if (!(v == 0u || v == 1u || v == 0x3F800000u)) ok = 0;
    }
    if (!ok) atomicAnd(&s_is4, 0);
    __syncthreads();
    int is4 = s_is4;
    const uint8_t* b8 = (const uint8_t*)adj_raw;
    int dg = 0;
    for (int w = 0; w < 8; ++w) {
      uint32_t word = 0;
      for (int jb = 0; jb < 32; ++jb) {
        int j = w * 32 + jb;
        int bit = is4 ? (u[tid * 256 + j] != 0u) : (b8[tid * 256 + j] != 0);
        if (bit) {
          word |= (1u << jb);
          if (dg < 64) nbr[tid * 64 + dg] = (uint8_t)j;
          dg++;
        }
      }
      adjbits[tid * 8 + w] = word;
    }
    deg[tid] = (dg > 64) ? 64 : dg;
    int c = 0;
    for (int cc = 0; cc < NC; ++cc) if (mask[cc * 256 + tid] != 0) c = cc;
    cls[tid] = c;
    __syncthreads();
    if (tid == 0) {
      int cn[NC];
      for (int i = 0; i < NC; ++i) cn[i] = 0;
      for (int r = 0; r < 256; ++r) {
        int cc = cls[r];
        if (cn[cc] < 64) lists[cc * 64 + cn[cc]] = r;
        cn[cc]++;
      }
      for (int i = 0; i < NC; ++i) cnt[i] = (cn[i] > 64) ? 64 : cn[i];
      for (int i = 0; i < NC * 256; ++i) midx[i] = -1;
      for (int cc = 0; cc < NC; ++cc)
        for (int i = 0; i < cnt[cc]; ++i)
          midx[cc * 256 + lists[cc * 64 + i]] = (int8_t)i;
    }
  } else {
    int c = blockIdx.x - 1;
    if (tid < 128) {
      float s1 = 0.f, s2 = 0.f;
      for (int g = 0; g < 64; ++g) {
        float w = W2[(c * 128 + tid) * 64 + g];
        s1 += w * a2d[c * 64 + g];
        s2 += w * a2s[c * 64 + g];
      }
      ud2[c * 128 + tid] = s1;
      us2[c * 128 + tid] = s2;
    }
  }
}

// ---------------------------------------------------------------------------
// k_prept: tiled transpose of weights to bf16, N-major ([n][k]) so MFMA
// b-fragments are contiguous 16B loads. 128 blocks x 256 threads.
// ---------------------------------------------------------------------------
__global__ void k_prept(const float* __restrict__ Wo, const float* __restrict__ Wk,
                        const float* __restrict__ Wv, const float* __restrict__ W1,
                        uint16_t* __restrict__ WOT, uint16_t* __restrict__ WKVT,
                        uint16_t* __restrict__ W1T)
{
  __shared__ float ts[64][65];
  int tid = threadIdx.x;
  int bid = blockIdx.x;
  const float* src;
  uint16_t* dst;
  int ncols, kt, nt;
  if (bid < 16)      { src = Wo; dst = WOT; ncols = 256; kt = bid >> 2; nt = bid & 3; }
  else if (bid < 32) { int t = bid - 16; src = Wk; dst = WKVT; ncols = 256; kt = t >> 2; nt = t & 3; }
  else if (bid < 48) { int t = bid - 32; src = Wv; dst = WKVT + 256 * 256; ncols = 256; kt = t >> 2; nt = t & 3; }
  else { int t = bid - 48; int c = t >> 3; int tt = t & 7;
         src = W1 + (long)c * 256 * 128; dst = W1T + (long)c * 128 * 256;
         ncols = 128; kt = tt >> 1; nt = tt & 1; }
  for (int idx = tid; idx < 4096; idx += 256) {
    int i = idx >> 6, j = idx & 63;
    ts[i][j] = src[(long)(kt * 64 + i) * ncols + nt * 64 + j];
  }
  __syncthreads();
  for (int idx = tid; idx < 4096; idx += 256) {
    int i = idx >> 6, j = idx & 63;
    dst[(long)(nt * 64 + i) * 256 + kt * 64 + j] = f2bf(ts[j][i]);
  }
}

// ---------------------------------------------------------------------------
// k_ruleq: rule embeddings (sparse multi-hot) + Q projection. Writes Q as
// bf16 pre-scaled by 1/8 (the attention scale) for direct MFMA a-frag use.
// ---------------------------------------------------------------------------
__global__ void k_ruleq(const float* __restrict__ basic, const float* __restrict__ cruc,
                        const float* __restrict__ Wtb, const float* __restrict__ btb,
                        const float* __restrict__ Wtk, const float* __restrict__ btk,
                        const float* __restrict__ Wq, const float* __restrict__ bq,
                        uint16_t* __restrict__ Qbf)
{
  __shared__ float row_s[2048];
  __shared__ float rule_s[256];
  __shared__ int   nzi[128];
  __shared__ float nzv[128];
  __shared__ int   nzc;
  int tid = threadIdx.x, r = blockIdx.x;
  float acc = btb[tid] + btk[tid];
  for (int m = 0; m < 2; ++m) {
    const float* src = m ? cruc : basic;
    const float* W   = m ? Wtk : Wtb;
    for (int idx = tid; idx < 2048; idx += 256)
      row_s[idx] = (idx < NV) ? src[r * NV + idx] : 0.0f;
    if (tid == 0) nzc = 0;
    __syncthreads();
    if (tid < 64) {
      int base = 0;
      for (int ch = 0; ch < 32; ++ch) {
        int idx = ch * 64 + tid;
        float v = row_s[idx];
        unsigned long long bm = __ballot(v != 0.0f);
        if (v != 0.0f) {
          int pos = base + (int)__popcll(bm & ((1ull << tid) - 1ull));
          if (pos < 128) { nzi[pos] = idx; nzv[pos] = v; }
        }
        base += (int)__popcll(bm);
      }
      if (tid == 0) nzc = (base > 128) ? 128 : base;
    }
    __syncthreads();
    int n = nzc;
    for (int t = 0; t < n; ++t) acc += nzv[t] * W[nzi[t] * 256 + tid];
    __syncthreads();
  }
  rule_s[tid] = acc;
  __syncthreads();
  float q = bq[tid];
  for (int k2 = 0; k2 < 256; ++k2) q += rule_s[k2] * Wq[k2 * 256 + tid];
  Qbf[r * 256 + tid] = f2bf(q * 0.125f);
}

// ---------------------------------------------------------------------------
// k_kvproj (MFMA): KX/VX = vis @ Wk/Wv + bias. Block = 64 rows x 64 cols.
// ---------------------------------------------------------------------------
__global__ __launch_bounds__(256) void k_kvproj(
    const float* __restrict__ vis, const uint16_t* __restrict__ WKVT,
    const float* __restrict__ bk, const float* __restrict__ bv,
    uint16_t* __restrict__ KX, uint16_t* __restrict__ VX)
{
  __shared__ uint16_t A_s[64 * 264];
  int tid = threadIdx.x;
  int lane = tid & 63, w = tid >> 6;
  int r15 = lane & 15, kg = lane >> 4;
  long m0 = (long)blockIdx.x * 64;
  int n0 = blockIdx.y * 64 + w * 16;
  for (int idx = tid; idx < 2048; idx += 256) {
    int r = idx >> 5, ch = idx & 31;
    const float4* p = (const float4*)&vis[(m0 + r) * 256 + ch * 8];
    float4 v0 = p[0], v1 = p[1];
    uint4 wd;
    wd.x = (uint32_t)f2bf(v0.x) | ((uint32_t)f2bf(v0.y) << 16);
    wd.y = (uint32_t)f2bf(v0.z) | ((uint32_t)f2bf(v0.w) << 16);
    wd.z = (uint32_t)f2bf(v1.x) | ((uint32_t)f2bf(v1.y) << 16);
    wd.w = (uint32_t)f2bf(v1.z) | ((uint32_t)f2bf(v1.w) << 16);
    *(uint4*)&A_s[r * 264 + ch * 8] = wd;
  }
  __syncthreads();
  const uint16_t* bptr = &WKVT[(long)(n0 + r15) * 256 + kg * 8];
  f32x4 acc[4];
  #pragma unroll
  for (int mt = 0; mt < 4; ++mt) acc[mt] = (f32x4){0.f, 0.f, 0.f, 0.f};
  #pragma unroll
  for (int ks = 0; ks < 8; ++ks) {
    bf16x8 bfr = *(const bf16x8*)(bptr + ks * 32);
    #pragma unroll
    for (int mt = 0; mt < 4; ++mt) {
      bf16x8 afr = *(const bf16x8*)&A_s[(mt * 16 + r15) * 264 + kg * 8 + ks * 32];
      acc[mt] = __builtin_amdgcn_mfma_f32_16x16x32_bf16(afr, bfr, acc[mt], 0, 0, 0);
    }
  }
  int col = n0 + r15;
  float bb = (col < 256) ? bk[col] : bv[col - 256];
  uint16_t* outp = (col < 256) ? KX : VX;
  int oc = (col < 256) ? col : col - 256;
  #pragma unroll
  for (int mt = 0; mt < 4; ++mt)
    #pragma unroll
    for (int j = 0; j < 4; ++j) {
      long row = m0 + mt * 16 + kg * 4 + j;
      outp[row * 256 + oc] = f2bf(acc[mt][j] + bb);
    }
}

// ---------------------------------------------------------------------------
// k_attn (MFMA): block = (batch b, half of rules), 512 thr / 8 waves.
// ---------------------------------------------------------------------------
__global__ __launch_bounds__(512) void k_attn(const uint16_t* __restrict__ Qbf,
                         const uint16_t* __restrict__ KX, const uint16_t* __restrict__ VX,
                         uint16_t* __restrict__ EMB)
{
  __shared__ uint16_t p_s[128 * 72];
  __shared__ uint16_t vt_s[64 * 72];
  int tid = threadIdx.x;
  int lane = tid & 63, w = tid >> 6;   // 8 waves
  int r15 = lane & 15, kg = lane >> 4;
  int b = blockIdx.x >> 1;
  int rbase = (blockIdx.x & 1) * 128;
  for (int h = 0; h < 4; ++h) {
    __syncthreads();  // prev head's vt_s reads done
    for (int idx = tid; idx < 2048; idx += 512) {
      int s = idx >> 5, d2 = (idx & 31) * 2;
      uint32_t v = *(const uint32_t*)&VX[((long)(b * 64 + s)) * 256 + h * 64 + d2];
      vt_s[d2 * 72 + s] = (uint16_t)(v & 0xffff);
      vt_s[(d2 + 1) * 72 + s] = (uint16_t)(v >> 16);
    }
    __syncthreads();
    f32x4 sacc[4];
    #pragma unroll
    for (int nt = 0; nt < 4; ++nt) sacc[nt] = (f32x4){0.f, 0.f, 0.f, 0.f};
    #pragma unroll
    for (int ks = 0; ks < 2; ++ks) {
      bf16x8 afr = *(const bf16x8*)&Qbf[(long)(rbase + w * 16 + r15) * 256 + h * 64 + ks * 32 + kg * 8];
      #pragma unroll
      for (int nt = 0; nt < 4; ++nt) {
        bf16x8 bfr = *(const bf16x8*)&KX[((long)(b * 64 + nt * 16 + r15)) * 256 + h * 64 + ks * 32 + kg * 8];
        sacc[nt] = __builtin_amdgcn_mfma_f32_16x16x32_bf16(afr, bfr, sacc[nt], 0, 0, 0);
      }
    }
    #pragma unroll
    for (int j = 0; j < 4; ++j) {
      float m = sacc[0][j];
      #pragma unroll
      for (int nt = 1; nt < 4; ++nt) m = fmaxf(m, sacc[nt][j]);
      m = fmaxf(m, __shfl_xor(m, 1));
      m = fmaxf(m, __shfl_xor(m, 2));
      m = fmaxf(m, __shfl_xor(m, 4));
      m = fmaxf(m, __shfl_xor(m, 8));
      float pv[4];
      float sum = 0.f;
      #pragma unroll
      for (int nt = 0; nt < 4; ++nt) { pv[nt] = __expf(sacc[nt][j] - m); sum += pv[nt]; }
      sum += __shfl_xor(sum, 1);
      sum += __shfl_xor(sum, 2);
      sum += __shfl_xor(sum, 4);
      sum += __shfl_xor(sum, 8);
      float rs = 1.0f / sum;
      #pragma unroll
      for (int nt = 0; nt < 4; ++nt)
        p_s[(w * 16 + kg * 4 + j) * 72 + nt * 16 + r15] = f2bf(pv[nt] * rs);
    }
    f32x4 oacc[4];
    #pragma unroll
    for (int nt = 0; nt < 4; ++nt) oacc[nt] = (f32x4){0.f, 0.f, 0.f, 0.f};
    #pragma unroll
    for (int ks = 0; ks < 2; ++ks) {
      bf16x8 afr = *(const bf16x8*)&p_s[(w * 16 + r15) * 72 + ks * 32 + kg * 8];
      #pragma unroll
      for (int nt = 0; nt < 4; ++nt) {
        bf16x8 bfr = *(const bf16x8*)&vt_s[(nt * 16 + r15) * 72 + ks * 32 + kg * 8];
        oacc[nt] = __builtin_amdgcn_mfma_f32_16x16x32_bf16(afr, bfr, oacc[nt], 0, 0, 0);
      }
    }
    #pragma unroll
    for (int nt = 0; nt < 4; ++nt)
      #pragma unroll
      for (int j = 0; j < 4; ++j) {
        long row = (long)(b * 256 + rbase + w * 16 + kg * 4 + j);
        EMB[row * 256 + h * 64 + nt * 16 + r15] = f2bf(oacc[nt][j]);
      }
  }
}

// ---------------------------------------------------------------------------
// k_wo (MFMA): EMB = EMB @ Wo + bo, in place. One block owns a 64-row range,
// stages all 256 cols once, computes 4 col-quadrants internally (race-free).
// ---------------------------------------------------------------------------
__global__ __launch_bounds__(256) void k_wo(uint16_t* __restrict__ EMB,
                    const uint16_t* __restrict__ WOT, const float* __restrict__ bo)
{
  __shared__ uint16_t A_s[64 * 264];
  int tid = threadIdx.x;
  int lane = tid & 63, w = tid >> 6;
  int r15 = lane & 15, kg = lane >> 4;
  long m0 = (long)blockIdx.x * 64;
  for (int idx = tid; idx < 2048; idx += 256) {
    int r = idx >> 5, ch = idx & 31;
    uint4 v = *(const uint4*)&EMB[(m0 + r) * 256 + ch * 8];
    *(uint4*)&A_s[r * 264 + ch * 8] = v;
  }
  __syncthreads();
  #pragma unroll
  for (int nt = 0; nt < 4; ++nt) {
    int n0 = nt * 64 + w * 16;
    const uint16_t* bptr = &WOT[(long)(n0 + r15) * 256 + kg * 8];
    f32x4 acc[4];
    #pragma unroll
    for (int mt = 0; mt < 4; ++mt) acc[mt] = (f32x4){0.f, 0.f, 0.f, 0.f};
    #pragma unroll
    for (int ks = 0; ks < 8; ++ks) {
      bf16x8 bfr = *(const bf16x8*)(bptr + ks * 32);
      #pragma unroll
      for (int mt = 0; mt < 4; ++mt) {
        bf16x8 afr = *(const bf16x8*)&A_s[(mt * 16 + r15) * 264 + kg * 8 + ks * 32];
        acc[mt] = __builtin_amdgcn_mfma_f32_16x16x32_bf16(afr, bfr, acc[mt], 0, 0, 0);
      }
    }
    int col = n0 + r15;
    float bb = bo[col];
    #pragma unroll
    for (int mt = 0; mt < 4; ++mt)
      #pragma unroll
      for (int j = 0; j < 4; ++j) {
        long row = m0 + mt * 16 + kg * 4 + j;
        EMB[row * 256 + col] = f2bf(acc[mt][j] + bb);
      }
  }
}

// ---------------------------------------------------------------------------
// k_gat v3 (fused hw1 + 2x MFMA GAT, short phases): per (c,b), 1024 thr.
// hW1 a-frags read DIRECTLY from global EMB (no A_s staging). Tail svec
// computed by all 1024 threads with coalesced W2 loads.
// ---------------------------------------------------------------------------
__global__ __launch_bounds__(1024) void k_gat(
    const uint16_t* __restrict__ EMB, const uint16_t* __restrict__ W1T,
    const float* __restrict__ a1d, const float* __restrict__ a1s,
    const int* __restrict__ lists, const int* __restrict__ cnt_g,
    const int* __restrict__ deg_g, const uint8_t* __restrict__ nbr_g,
    const int8_t* __restrict__ midx_g,
    const float* __restrict__ b1, const float* __restrict__ ud2_g,
    const float* __restrict__ us2_g, const float* __restrict__ W2,
    const float* __restrict__ b2, const float* __restrict__ Wl,
    const float* __restrict__ bl, float* __restrict__ out)
{
  __shared__ uint16_t alpha_s[256 * 72]; // [r][jm] unnormalized alpha, bf16
  __shared__ uint16_t hwt_s[128 * 72];   // hW1^T: [f][jm], stride 72
  __shared__ float e1d_s[256], e1s_s[256], rd1_s[256];
  __shared__ float e2d_s[256], e2s_s[256], rd2_s[256], wj_s[256];
  __shared__ float a1d_s[128], a1s_s[128], b1_s[128], ud2_s[128], us2_s[128];
  __shared__ float tpart[16][128];
  __shared__ float t_s[128], svec[64], lvec[8];
  __shared__ int   list_s[64];
  int tid = threadIdx.x;
  int lane = tid & 63, w = tid >> 6;
  int r15 = lane & 15, kg = lane >> 4;
  int c = blockIdx.x >> 8, b = blockIdx.x & 255;
  int n = cnt_g[c];
  if (tid < 64) list_s[tid] = (tid < n) ? lists[c * 64 + tid] : 0;
  if (tid < 128) {
    a1d_s[tid] = a1d[c * 128 + tid];
    a1s_s[tid] = a1s[c * 128 + tid];
    b1_s[tid]  = b1[c * 128 + tid];
    ud2_s[tid] = ud2_g[c * 128 + tid];
    us2_s[tid] = us2_g[c * 128 + tid];
  }
  if (tid < 256) { e1d_s[tid] = 0.f; e1s_s[tid] = 0.f; }
  __syncthreads();  // B0
  // P2: hW1 MFMA, wave = (mt = w&3 rows, nh = w>>2 col-pair), A from global.
  int mt = w & 3, nh = w >> 2;
  int colA = nh * 32 + r15, colB = colA + 16;
  const uint16_t* bptr = &W1T[((long)c * 128 + colA) * 256 + kg * 8];
  const uint16_t* arow = &EMB[((long)b * 256 + list_s[mt * 16 + r15]) * 256 + kg * 8];
  f32x4 acc0 = (f32x4){0.f, 0.f, 0.f, 0.f};
  f32x4 acc1 = (f32x4){0.f, 0.f, 0.f, 0.f};
  if (mt * 16 < n) {
    #pragma unroll
    for (int ks = 0; ks < 8; ++ks) {
      bf16x8 b0 = *(const bf16x8*)(bptr + ks * 32);
      bf16x8 b1f = *(const bf16x8*)(bptr + 16 * 256 + ks * 32);
      bf16x8 afr = *(const bf16x8*)(arow + ks * 32);
      acc0 = __builtin_amdgcn_mfma_f32_16x16x32_bf16(afr, b0, acc0, 0, 0, 0);
      acc1 = __builtin_amdgcn_mfma_f32_16x16x32_bf16(afr, b1f, acc1, 0, 0, 0);
    }
  }
  // P3: write hwt (transposed bf16) + pd/ps fragment dots -> tpart
  {
    uint2 pA, pB;
    pA.x = (uint32_t)f2bf(acc0[0]) | ((uint32_t)f2bf(acc0[1]) << 16);
    pA.y = (uint32_t)f2bf(acc0[2]) | ((uint32_t)f2bf(acc0[3]) << 16);
    pB.x = (uint32_t)f2bf(acc1[0]) | ((uint32_t)f2bf(acc1[1]) << 16);
    pB.y = (uint32_t)f2bf(acc1[2]) | ((uint32_t)f2bf(acc1[3]) << 16);
    *(uint2*)&hwt_s[colA * 72 + mt * 16 + kg * 4] = pA;
    *(uint2*)&hwt_s[colB * 72 + mt * 16 + kg * 4] = pB;
    float adA = a1d_s[colA], adB = a1d_s[colB];
    float asA = a1s_s[colA], asB = a1s_s[colB];
    #pragma unroll
    for (int j = 0; j < 4; ++j) {
      float pd = acc0[j] * adA + acc1[j] * adB;
      float ps = acc0[j] * asA + acc1[j] * asB;
      pd += __shfl_xor(pd, 1); pd += __shfl_xor(pd, 2);
      pd += __shfl_xor(pd, 4); pd += __shfl_xor(pd, 8);
      ps += __shfl_xor(ps, 1); ps += __shfl_xor(ps, 2);
      ps += __shfl_xor(ps, 4); ps += __shfl_xor(ps, 8);
      if (r15 == 0) {
        int jm = mt * 16 + kg * 4 + j;
        tpart[nh][jm] = pd;
        tpart[nh][jm + 64] = ps;
      }
    }
  }
  __syncthreads();  // B1
  // P4: combine e1d/e1s (members) + zero own alpha row slice
  int r = tid >> 2, q = tid & 3;
  {
    uint32_t* zp = (uint32_t*)&alpha_s[r * 72 + q * 18];
    #pragma unroll
    for (int i = 0; i < 9; ++i) zp[i] = 0u;
  }
  if (tid < 64 && tid < n) {
    float sd = tpart[0][tid] + tpart[1][tid] + tpart[2][tid] + tpart[3][tid];
    float ss = tpart[0][tid + 64] + tpart[1][tid + 64] + tpart[2][tid + 64] + tpart[3][tid + 64];
    int rr = list_s[tid];
    e1d_s[rr] = sd;
    e1s_s[rr] = ss;
  }
  __syncthreads();  // B2
  // P5: alpha scatter + den1
  int dg = deg_g[r];
  {
    float e1dv = e1d_s[r];
    float den = 0.f;
    for (int t = q; t < dg; t += 4) {
      int j = nbr_g[r * 64 + t];
      float e = e1dv + e1s_s[j];
      e = fmaxf(e, 0.2f * e);
      e = fminf(e, 60.f);
      float wv = __expf(e);
      den += wv;
      int mi = midx_g[c * 256 + j];
      if (mi >= 0) alpha_s[r * 72 + mi] = f2bf(wv);
    }
    den += __shfl_xor(den, 1);
    den += __shfl_xor(den, 2);
    if (q == 0) rd1_s[r] = 1.0f / den;
  }
  __syncthreads();  // B3
  // P6: G = alpha @ hwt via MFMA. wave w -> rules w*16..+15, 8 n-tiles.
  f32x4 g[8];
  #pragma unroll
  for (int nt = 0; nt < 8; ++nt) g[nt] = (f32x4){0.f, 0.f, 0.f, 0.f};
  int kslices = (n > 32) ? 2 : 1;
  for (int ks = 0; ks < kslices; ++ks) {
    bf16x8 afr = *(const bf16x8*)&alpha_s[(w * 16 + r15) * 72 + ks * 32 + kg * 8];
    #pragma unroll
    for (int nt = 0; nt < 8; ++nt) {
      bf16x8 bfr = *(const bf16x8*)&hwt_s[(nt * 16 + r15) * 72 + ks * 32 + kg * 8];
      g[nt] = __builtin_amdgcn_mfma_f32_16x16x32_bf16(afr, bfr, g[nt], 0, 0, 0);
    }
  }
  // P7: epilogue: g = relu(G*rd1 + b1); e2 dots
  {
    float rd1v[4];
    #pragma unroll
    for (int j = 0; j < 4; ++j) rd1v[j] = rd1_s[w * 16 + kg * 4 + j];
    float ed[4] = {0.f, 0.f, 0.f, 0.f}, es[4] = {0.f, 0.f, 0.f, 0.f};
    #pragma unroll
    for (int nt = 0; nt < 8; ++nt) {
      float uf = ud2_s[nt * 16 + r15], sf = us2_s[nt * 16 + r15];
      float bf = b1_s[nt * 16 + r15];
      #pragma unroll
      for (int j = 0; j < 4; ++j) {
        float gv = fmaxf(g[nt][j] * rd1v[j] + bf, 0.f);
        g[nt][j] = gv;
        ed[j] += gv * uf;
        es[j] += gv * sf;
      }
    }
    #pragma unroll
    for (int j = 0; j < 4; ++j) {
      ed[j] += __shfl_xor(ed[j], 1); ed[j] += __shfl_xor(ed[j], 2);
      ed[j] += __shfl_xor(ed[j], 4); ed[j] += __shfl_xor(ed[j], 8);
      es[j] += __shfl_xor(es[j], 1); es[j] += __shfl_xor(es[j], 2);
      es[j] += __shfl_xor(es[j], 4); es[j] += __shfl_xor(es[j], 8);
      if (r15 == 0) {
        e2d_s[w * 16 + kg * 4 + j] = ed[j];
        e2s_s[w * 16 + kg * 4 + j] = es[j];
      }
    }
  }
  __syncthreads();  // B4
  // P8: den2
  {
    float e2dv = e2d_s[r];
    float den2 = 0.f;
    for (int t = q; t < dg; t += 4) {
      int j = nbr_g[r * 64 + t];
      float e = e2dv + e2s_s[j];
      e = fmaxf(e, 0.2f * e);
      e = fminf(e, 60.f);
      den2 += __expf(e);
    }
    den2 += __shfl_xor(den2, 1);
    den2 += __shfl_xor(den2, 2);
    if (q == 0) rd2_s[r] = 1.0f / den2;
  }
  __syncthreads();  // B5
  // P9: column weights wj[r] = sum_i alpha2[i,r]
  {
    float e2sv = e2s_s[r];
    float wj = 0.f;
    for (int t = q; t < dg; t += 4) {
      int i2 = nbr_g[r * 64 + t];
      float e = e2d_s[i2] + e2sv;
      e = fmaxf(e, 0.2f * e);
      e = fminf(e, 60.f);
      wj += __expf(e) * rd2_s[i2];
    }
    wj += __shfl_xor(wj, 1);
    wj += __shfl_xor(wj, 2);
    if (q == 0) wj_s[r] = wj;
  }
  __syncthreads();  // B6
  // P10: t partials from live fragments
  {
    float wjv[4];
    #pragma unroll
    for (int j = 0; j < 4; ++j) wjv[j] = wj_s[w * 16 + kg * 4 + j];
    #pragma unroll
    for (int nt = 0; nt < 8; ++nt) {
      float tp = wjv[0] * g[nt][0] + wjv[1] * g[nt][1] + wjv[2] * g[nt][2] + wjv[3] * g[nt][3];
      tp += __shfl_xor(tp, 16);
      tp += __shfl_xor(tp, 32);
      if (kg == 0) tpart[w][nt * 16 + r15] = tp;
    }
  }
  __syncthreads();  // B7
  // P11: t combine
  if (tid < 128) {
    float s = 0.f;
    #pragma unroll
    for (int w2 = 0; w2 < 16; ++w2) s += tpart[w2][tid];
    t_s[tid] = s;
  }
  __syncthreads();  // B8
  // P12: svec partials: all 1024 threads, coalesced W2 reads.
  {
    int col = tid & 63, fg = tid >> 6;
    float sp = 0.f;
    #pragma unroll
    for (int i = 0; i < 8; ++i) {
      int f = fg * 8 + i;
      sp += t_s[f] * W2[((long)c * 128 + f) * 64 + col];
    }
    tpart[fg][col] = sp;
  }
  __syncthreads();  // B9
  if (tid < 64) {
    float s = 256.0f * b2[c * 64 + tid];
    #pragma unroll
    for (int fg = 0; fg < 16; ++fg) s += tpart[fg][tid];
    svec[tid] = s;
  }
  __syncthreads();  // B10
  if (tid < 6) {
    float lg = 256.0f * bl[c * 6 + tid];
    for (int f = 0; f < 64; ++f) lg += svec[f] * Wl[((long)c * 64 + f) * 6 + tid];
    lvec[tid] = lg;
  }
  __syncthreads();  // B11
  if (tid == 0) {
    float mm = lvec[0];
    for (int k2 = 1; k2 < 6; ++k2) mm = fmaxf(mm, lvec[k2]);
    float ss = 0.f;
    for (int k2 = 0; k2 < 6; ++k2) ss += __expf(lvec[k2] - mm);
    float lse = mm + __logf(ss);
    for (int k2 = 0; k2 < 6; ++k2) out[((long)c * 256 + b) * 6 + k2] = lvec[k2] - lse;
  }
}

// ---------------------------------------------------------------------------
extern "C" void kernel_launch(void* const* d_in, const int* in_sizes, int n_in,
                              void* d_out, int out_size, void* d_ws, size_t ws_size,
                              hipStream_t stream)
{
  const float* vis   = (const float*)d_in[0];
  const float* basic = (const float*)d_in[1];
  const float* cruc  = (const float*)d_in[2];
  const float* Wtb   = (const float*)d_in[3];
  const float* btb   = (const float*)d_in[4];
  const float* Wtk   = (const float*)d_in[5];
  const float* btk   = (const float*)d_in[6];
  const float* Wq    = (const float*)d_in[7];
  const float* bq    = (const float*)d_in[8];
  const float* Wk    = (const float*)d_in[9];
  const float* bk    = (const float*)d_in[10];
  const float* Wv    = (const float*)d_in[11];
  const float* bv    = (const float*)d_in[12];
  const float* Wo    = (const float*)d_in[13];
  const float* bo    = (const float*)d_in[14];
  const float* W1    = (const float*)d_in[15];
  const float* a1s   = (const float*)d_in[16];
  const float* a1d   = (const float*)d_in[17];
  const float* b1    = (const float*)d_in[18];
  const float* W2    = (const float*)d_in[19];
  const float* a2s   = (const float*)d_in[20];
  const float* a2d   = (const float*)d_in[21];
  const float* b2    = (const float*)d_in[22];
  const float* Wl    = (const float*)d_in[23];
  const float* bl    = (const float*)d_in[24];
  const void*  adj   = d_in[25];
  const int*   mask  = (const int*)d_in[26];
  float* out = (float*)d_out;
  char* ws = (char*)d_ws;

  uint16_t* QBF  = (uint16_t*)(ws + 0);         // 131072
  uint32_t* ADJ  = (uint32_t*)(ws + 262144);    // 8192
  int*      CLS  = (int*)(ws + 270336);         // 1024
  int*      LST  = (int*)(ws + 271360);         // 2560
  int*      CNT  = (int*)(ws + 273920);         // 64
  int*      DEG  = (int*)(ws + 273984);         // 1024
  uint8_t*  NBR  = (uint8_t*)(ws + 275008);     // 16384
  int8_t*   MIDX = (int8_t*)(ws + 291392);      // 2560
  float*    UD2  = (float*)(ws + 293952);       // 5120
  float*    US2  = (float*)(ws + 299072);       // 5120
  uint16_t* WOT  = (uint16_t*)(ws + 304192);    // 131072
  uint16_t* WKVT = (uint16_t*)(ws + 435264);    // 262144
  uint16_t* W1T  = (uint16_t*)(ws + 697408);    // 655360
  uint16_t* KX   = (uint16_t*)(ws + 1352768);   // 8388608
  uint16_t* VX   = (uint16_t*)(ws + 9741376);   // 8388608
  uint16_t* EMB  = (uint16_t*)(ws + 18129984);  // 33554432 -> total ~49.3 MiB

  hipLaunchKernelGGL(k_prep, dim3(11), dim3(256), 0, stream,
                     adj, mask, W2, a2s, a2d, ADJ, CLS, LST, CNT, DEG, NBR, MIDX, UD2, US2);
  hipLaunchKernelGGL(k_prept, dim3(128), dim3(256), 0, stream,
                     Wo, Wk, Wv, W1, WOT, WKVT, W1T);
  hipLaunchKernelGGL(k_ruleq, dim3(256), dim3(256), 0, stream,
                     basic, cruc, Wtb, btb, Wtk, btk, Wq, bq, QBF);
  hipLaunchKernelGGL(k_kvproj, dim3(256, 8), dim3(256), 0, stream,
                     vis, WKVT, bk, bv, KX, VX);
  hipLaunchKernelGGL(k_attn, dim3(512), dim3(512), 0, stream, QBF, KX, VX, EMB);
  hipLaunchKernelGGL(k_wo, dim3(1024), dim3(256), 0, stream, EMB, WOT, bo);
  hipLaunchKernelGGL(k_gat, dim3(2560), dim3(1024), 0, stream,
                     EMB, W1T, a1d, a1s, LST, CNT, DEG, NBR, MIDX,
                     b1, UD2, US2, W2, b2, Wl, bl, out);
}

// Round 10
// 416.117 us; speedup vs baseline: 1.7231x; 1.0738x over previous
//
#include <hip/hip_runtime.h>
#include <stdint.h>

// Sizes (fixed by the problem)
#define NB 256
#define NS 64
#define NR 256
#define NV 2000
#define NC 10
#define NK 6
#define ND 256

typedef __attribute__((ext_vector_type(8))) short bf16x8;
typedef __attribute__((ext_vector_type(4))) float f32x4;

__device__ __forceinline__ float bf2f(uint16_t u) {
  return __uint_as_float(((uint32_t)u) << 16);
}
__device__ __forceinline__ uint16_t f2bf(float f) {
  uint32_t x = __float_as_uint(f);
  x += 0x7FFFu + ((x >> 16) & 1u);
  return (uint16_t)(x >> 16);
}

// ---------------------------------------------------------------------------
// k_front: merged independent preprocessing.
//   blocks 0..10    : k_prep  (adjacency/bitmask/lists/midx + ud2/us2)
//   blocks 11..138  : k_prept (weight transposes to bf16 N-major)
//   blocks 139..394 : k_ruleq (rule embeddings + Q proj, bf16*0.125)
//   blocks 395..2442: k_kvproj (KX/VX = vis @ Wk/Wv + bias, MFMA)
// ---------------------------------------------------------------------------
__global__ __launch_bounds__(256) void k_front(
    const void* __restrict__ adj_raw, const int* __restrict__ mask,
    const float* __restrict__ W2, const float* __restrict__ a2s,
    const float* __restrict__ a2d,
    uint32_t* __restrict__ adjbits, int* __restrict__ cls,
    int* __restrict__ lists, int* __restrict__ cnt,
    int* __restrict__ deg, uint8_t* __restrict__ nbr,
    int8_t* __restrict__ midx,
    float* __restrict__ ud2, float* __restrict__ us2,
    const float* __restrict__ Wo, const float* __restrict__ Wk,
    const float* __restrict__ Wv, const float* __restrict__ W1,
    uint16_t* __restrict__ WOT, uint16_t* __restrict__ WKVT,
    uint16_t* __restrict__ W1T,
    const float* __restrict__ basic, const float* __restrict__ cruc,
    const float* __restrict__ Wtb, const float* __restrict__ btb,
    const float* __restrict__ Wtk, const float* __restrict__ btk,
    const float* __restrict__ Wq, const float* __restrict__ bq,
    uint16_t* __restrict__ Qbf,
    const float* __restrict__ vis, const float* __restrict__ bk,
    const float* __restrict__ bv,
    uint16_t* __restrict__ KX, uint16_t* __restrict__ VX)
{
  __shared__ char smem[33792];
  int bid = blockIdx.x;
  int tid = threadIdx.x;
  if (bid < 11) {
    // ---- k_prep ----
    if (bid == 0) {
      int* s_is4 = (int*)smem;
      if (tid == 0) *s_is4 = 1;
      __syncthreads();
      const uint32_t* u = (const uint32_t*)adj_raw;
      int ok = 1;
      for (int idx = tid; idx < 16384; idx += 256) {
        uint32_t v = u[idx];
        if (!(v == 0u || v == 1u || v == 0x3F800000u)) ok = 0;
      }
      if (!ok) atomicAnd(s_is4, 0);
      __syncthreads();
      int is4 = *s_is4;
      const uint8_t* b8 = (const uint8_t*)adj_raw;
      int dg = 0;
      for (int w = 0; w < 8; ++w) {
        uint32_t word = 0;
        for (int jb = 0; jb < 32; ++jb) {
          int j = w * 32 + jb;
          int bit = is4 ? (u[tid * 256 + j] != 0u) : (b8[tid * 256 + j] != 0);
          if (bit) {
            word |= (1u << jb);
            if (dg < 64) nbr[tid * 64 + dg] = (uint8_t)j;
            dg++;
          }
        }
        adjbits[tid * 8 + w] = word;
      }
      deg[tid] = (dg > 64) ? 64 : dg;
      int c = 0;
      for (int cc = 0; cc < NC; ++cc) if (mask[cc * 256 + tid] != 0) c = cc;
      cls[tid] = c;
      __syncthreads();
      if (tid == 0) {
        int cn[NC];
        for (int i = 0; i < NC; ++i) cn[i] = 0;
        for (int r = 0; r < 256; ++r) {
          int cc = cls[r];
          if (cn[cc] < 64) lists[cc * 64 + cn[cc]] = r;
          cn[cc]++;
        }
        for (int i = 0; i < NC; ++i) cnt[i] = (cn[i] > 64) ? 64 : cn[i];
        for (int i = 0; i < NC * 256; ++i) midx[i] = -1;
        for (int cc = 0; cc < NC; ++cc)
          for (int i = 0; i < cnt[cc]; ++i)
            midx[cc * 256 + lists[cc * 64 + i]] = (int8_t)i;
      }
    } else {
      int c = bid - 1;
      if (tid < 128) {
        float s1 = 0.f, s2 = 0.f;
        for (int g = 0; g < 64; ++g) {
          float w = W2[(c * 128 + tid) * 64 + g];
          s1 += w * a2d[c * 64 + g];
          s2 += w * a2s[c * 64 + g];
        }
        ud2[c * 128 + tid] = s1;
        us2[c * 128 + tid] = s2;
      }
    }
  } else if (bid < 139) {
    // ---- k_prept ----
    float (*ts)[65] = (float(*)[65])smem;
    int pb = bid - 11;
    const float* src;
    uint16_t* dst;
    int ncols, kt, nt;
    if (pb < 16)      { src = Wo; dst = WOT; ncols = 256; kt = pb >> 2; nt = pb & 3; }
    else if (pb < 32) { int t = pb - 16; src = Wk; dst = WKVT; ncols = 256; kt = t >> 2; nt = t & 3; }
    else if (pb < 48) { int t = pb - 32; src = Wv; dst = WKVT + 256 * 256; ncols = 256; kt = t >> 2; nt = t & 3; }
    else { int t = pb - 48; int c = t >> 3; int tt = t & 7;
           src = W1 + (long)c * 256 * 128; dst = W1T + (long)c * 128 * 256;
           ncols = 128; kt = tt >> 1; nt = tt & 1; }
    for (int idx = tid; idx < 4096; idx += 256) {
      int i = idx >> 6, j = idx & 63;
      ts[i][j] = src[(long)(kt * 64 + i) * ncols + nt * 64 + j];
    }
    __syncthreads();
    for (int idx = tid; idx < 4096; idx += 256) {
      int i = idx >> 6, j = idx & 63;
      dst[(long)(nt * 64 + i) * 256 + kt * 64 + j] = f2bf(ts[j][i]);
    }
  } else if (bid < 395) {
    // ---- k_ruleq ----
    float* row_s  = (float*)smem;              // 2048 f
    float* rule_s = row_s + 2048;              // 256 f
    int*   nzi    = (int*)(rule_s + 256);      // 128 i
    float* nzv    = (float*)(nzi + 128);       // 128 f
    int*   nzcp   = (int*)(nzv + 128);         // 1 i
    int r = bid - 139;
    float acc = btb[tid] + btk[tid];
    for (int m = 0; m < 2; ++m) {
      const float* src = m ? cruc : basic;
      const float* W   = m ? Wtk : Wtb;
      for (int idx = tid; idx < 2048; idx += 256)
        row_s[idx] = (idx < NV) ? src[r * NV + idx] : 0.0f;
      if (tid == 0) *nzcp = 0;
      __syncthreads();
      if (tid < 64) {
        int base = 0;
        for (int ch = 0; ch < 32; ++ch) {
          int idx = ch * 64 + tid;
          float v = row_s[idx];
          unsigned long long bm = __ballot(v != 0.0f);
          if (v != 0.0f) {
            int pos = base + (int)__popcll(bm & ((1ull << tid) - 1ull));
            if (pos < 128) { nzi[pos] = idx; nzv[pos] = v; }
          }
          base += (int)__popcll(bm);
        }
        if (tid == 0) *nzcp = (base > 128) ? 128 : base;
      }
      __syncthreads();
      int n = *nzcp;
      for (int t = 0; t < n; ++t) acc += nzv[t] * W[nzi[t] * 256 + tid];
      __syncthreads();
    }
    rule_s[tid] = acc;
    __syncthreads();
    float q = bq[tid];
    for (int k2 = 0; k2 < 256; ++k2) q += rule_s[k2] * Wq[k2 * 256 + tid];
    Qbf[r * 256 + tid] = f2bf(q * 0.125f);
  } else {
    // ---- k_kvproj ----
    uint16_t* A_s = (uint16_t*)smem;  // 64 x 264
    int t = bid - 395;
    int bx = t & 255, by = t >> 8;
    int lane = tid & 63, w = tid >> 6;
    int r15 = lane & 15, kg = lane >> 4;
    long m0 = (long)bx * 64;
    int n0 = by * 64 + w * 16;
    for (int idx = tid; idx < 2048; idx += 256) {
      int r = idx >> 5, ch = idx & 31;
      const float4* p = (const float4*)&vis[(m0 + r) * 256 + ch * 8];
      float4 v0 = p[0], v1 = p[1];
      uint4 wd;
      wd.x = (uint32_t)f2bf(v0.x) | ((uint32_t)f2bf(v0.y) << 16);
      wd.y = (uint32_t)f2bf(v0.z) | ((uint32_t)f2bf(v0.w) << 16);
      wd.z = (uint32_t)f2bf(v1.x) | ((uint32_t)f2bf(v1.y) << 16);
      wd.w = (uint32_t)f2bf(v1.z) | ((uint32_t)f2bf(v1.w) << 16);
      *(uint4*)&A_s[r * 264 + ch * 8] = wd;
    }
    __syncthreads();
    const uint16_t* bptr = &WKVT[(long)(n0 + r15) * 256 + kg * 8];
    f32x4 acc[4];
    #pragma unroll
    for (int mt = 0; mt < 4; ++mt) acc[mt] = (f32x4){0.f, 0.f, 0.f, 0.f};
    #pragma unroll
    for (int ks = 0; ks < 8; ++ks) {
      bf16x8 bfr = *(const bf16x8*)(bptr + ks * 32);
      #pragma unroll
      for (int mt = 0; mt < 4; ++mt) {
        bf16x8 afr = *(const bf16x8*)&A_s[(mt * 16 + r15) * 264 + kg * 8 + ks * 32];
        acc[mt] = __builtin_amdgcn_mfma_f32_16x16x32_bf16(afr, bfr, acc[mt], 0, 0, 0);
      }
    }
    int col = n0 + r15;
    float bb = (col < 256) ? bk[col] : bv[col - 256];
    uint16_t* outp = (col < 256) ? KX : VX;
    int oc = (col < 256) ? col : col - 256;
    #pragma unroll
    for (int mt = 0; mt < 4; ++mt)
      #pragma unroll
      for (int j = 0; j < 4; ++j) {
        long row = m0 + mt * 16 + kg * 4 + j;
        outp[row * 256 + oc] = f2bf(acc[mt][j] + bb);
      }
  }
}

// ---------------------------------------------------------------------------
// k_attn (MFMA): block = (batch b, half of rules), 512 thr / 8 waves.
// ---------------------------------------------------------------------------
__global__ __launch_bounds__(512) void k_attn(const uint16_t* __restrict__ Qbf,
                         const uint16_t* __restrict__ KX, const uint16_t* __restrict__ VX,
                         uint16_t* __restrict__ EMB)
{
  __shared__ uint16_t p_s[128 * 72];
  __shared__ uint16_t vt_s[64 * 72];
  int tid = threadIdx.x;
  int lane = tid & 63, w = tid >> 6;   // 8 waves
  int r15 = lane & 15, kg = lane >> 4;
  int b = blockIdx.x >> 1;
  int rbase = (blockIdx.x & 1) * 128;
  for (int h = 0; h < 4; ++h) {
    __syncthreads();  // prev head's vt_s reads done
    for (int idx = tid; idx < 2048; idx += 512) {
      int s = idx >> 5, d2 = (idx & 31) * 2;
      uint32_t v = *(const uint32_t*)&VX[((long)(b * 64 + s)) * 256 + h * 64 + d2];
      vt_s[d2 * 72 + s] = (uint16_t)(v & 0xffff);
      vt_s[(d2 + 1) * 72 + s] = (uint16_t)(v >> 16);
    }
    __syncthreads();
    f32x4 sacc[4];
    #pragma unroll
    for (int nt = 0; nt < 4; ++nt) sacc[nt] = (f32x4){0.f, 0.f, 0.f, 0.f};
    #pragma unroll
    for (int ks = 0; ks < 2; ++ks) {
      bf16x8 afr = *(const bf16x8*)&Qbf[(long)(rbase + w * 16 + r15) * 256 + h * 64 + ks * 32 + kg * 8];
      #pragma unroll
      for (int nt = 0; nt < 4; ++nt) {
        bf16x8 bfr = *(const bf16x8*)&KX[((long)(b * 64 + nt * 16 + r15)) * 256 + h * 64 + ks * 32 + kg * 8];
        sacc[nt] = __builtin_amdgcn_mfma_f32_16x16x32_bf16(afr, bfr, sacc[nt], 0, 0, 0);
      }
    }
    #pragma unroll
    for (int j = 0; j < 4; ++j) {
      float m = sacc[0][j];
      #pragma unroll
      for (int nt = 1; nt < 4; ++nt) m = fmaxf(m, sacc[nt][j]);
      m = fmaxf(m, __shfl_xor(m, 1));
      m = fmaxf(m, __shfl_xor(m, 2));
      m = fmaxf(m, __shfl_xor(m, 4));
      m = fmaxf(m, __shfl_xor(m, 8));
      float pv[4];
      float sum = 0.f;
      #pragma unroll
      for (int nt = 0; nt < 4; ++nt) { pv[nt] = __expf(sacc[nt][j] - m); sum += pv[nt]; }
      sum += __shfl_xor(sum, 1);
      sum += __shfl_xor(sum, 2);
      sum += __shfl_xor(sum, 4);
      sum += __shfl_xor(sum, 8);
      float rs = 1.0f / sum;
      #pragma unroll
      for (int nt = 0; nt < 4; ++nt)
        p_s[(w * 16 + kg * 4 + j) * 72 + nt * 16 + r15] = f2bf(pv[nt] * rs);
    }
    f32x4 oacc[4];
    #pragma unroll
    for (int nt = 0; nt < 4; ++nt) oacc[nt] = (f32x4){0.f, 0.f, 0.f, 0.f};
    #pragma unroll
    for (int ks = 0; ks < 2; ++ks) {
      bf16x8 afr = *(const bf16x8*)&p_s[(w * 16 + r15) * 72 + ks * 32 + kg * 8];
      #pragma unroll
      for (int nt = 0; nt < 4; ++nt) {
        bf16x8 bfr = *(const bf16x8*)&vt_s[(nt * 16 + r15) * 72 + ks * 32 + kg * 8];
        oacc[nt] = __builtin_amdgcn_mfma_f32_16x16x32_bf16(afr, bfr, oacc[nt], 0, 0, 0);
      }
    }
    #pragma unroll
    for (int nt = 0; nt < 4; ++nt)
      #pragma unroll
      for (int j = 0; j < 4; ++j) {
        long row = (long)(b * 256 + rbase + w * 16 + kg * 4 + j);
        EMB[row * 256 + h * 64 + nt * 16 + r15] = f2bf(oacc[nt][j]);
      }
  }
}

// ---------------------------------------------------------------------------
// k_wo (MFMA): EMB = EMB @ Wo + bo, in place (race-free per 64-row block).
// ---------------------------------------------------------------------------
__global__ __launch_bounds__(256) void k_wo(uint16_t* __restrict__ EMB,
                    const uint16_t* __restrict__ WOT, const float* __restrict__ bo)
{
  __shared__ uint16_t A_s[64 * 264];
  int tid = threadIdx.x;
  int lane = tid & 63, w = tid >> 6;
  int r15 = lane & 15, kg = lane >> 4;
  long m0 = (long)blockIdx.x * 64;
  for (int idx = tid; idx < 2048; idx += 256) {
    int r = idx >> 5, ch = idx & 31;
    uint4 v = *(const uint4*)&EMB[(m0 + r) * 256 + ch * 8];
    *(uint4*)&A_s[r * 264 + ch * 8] = v;
  }
  __syncthreads();
  #pragma unroll
  for (int nt = 0; nt < 4; ++nt) {
    int n0 = nt * 64 + w * 16;
    const uint16_t* bptr = &WOT[(long)(n0 + r15) * 256 + kg * 8];
    f32x4 acc[4];
    #pragma unroll
    for (int mt = 0; mt < 4; ++mt) acc[mt] = (f32x4){0.f, 0.f, 0.f, 0.f};
    #pragma unroll
    for (int ks = 0; ks < 8; ++ks) {
      bf16x8 bfr = *(const bf16x8*)(bptr + ks * 32);
      #pragma unroll
      for (int mt = 0; mt < 4; ++mt) {
        bf16x8 afr = *(const bf16x8*)&A_s[(mt * 16 + r15) * 264 + kg * 8 + ks * 32];
        acc[mt] = __builtin_amdgcn_mfma_f32_16x16x32_bf16(afr, bfr, acc[mt], 0, 0, 0);
      }
    }
    int col = n0 + r15;
    float bb = bo[col];
    #pragma unroll
    for (int mt = 0; mt < 4; ++mt)
      #pragma unroll
      for (int j = 0; j < 4; ++j) {
        long row = m0 + mt * 16 + kg * 4 + j;
        EMB[row * 256 + col] = f2bf(acc[mt][j] + bb);
      }
  }
}

// ---------------------------------------------------------------------------
// k_gat v4: fused hw1 + 2x MFMA GAT. LDS < 64KB via aliasing (tpart->alpha,
// pd/ps->e2d/e2s, svec/lvec->hwt, wj->rd1). Neighbor bytes prefetched to
// registers (chunked per q, static word indexing) and reused in all 3
// neighbor phases.
// ---------------------------------------------------------------------------
__global__ __launch_bounds__(1024) void k_gat(
    const uint16_t* __restrict__ EMB, const uint16_t* __restrict__ W1T,
    const float* __restrict__ a1d, const float* __restrict__ a1s,
    const int* __restrict__ lists, const int* __restrict__ cnt_g,
    const int* __restrict__ deg_g, const uint8_t* __restrict__ nbr_g,
    const int8_t* __restrict__ midx_g,
    const float* __restrict__ b1, const float* __restrict__ ud2_g,
    const float* __restrict__ us2_g, const float* __restrict__ W2,
    const float* __restrict__ b2, const float* __restrict__ Wl,
    const float* __restrict__ bl, float* __restrict__ out)
{
  __shared__ uint16_t alpha_s[256 * 72]; // [r][jm] unnorm alpha; later: tpart
  __shared__ uint16_t hwt_s[128 * 72];   // hW1^T [f][jm]; later: svec/lvec
  __shared__ float e1d_s[256], e1s_s[256], rd1_s[256];
  __shared__ float e2d_s[256], e2s_s[256], rd2_s[256];
  __shared__ float a1d_s[128], a1s_s[128], b1_s[128], ud2_s[128], us2_s[128];
  __shared__ float t_s[128];
  __shared__ int   list_s[64];
  float (*tpart)[128] = (float(*)[128])alpha_s;  // alias (alpha dead after P6)
  float* wj_s = rd1_s;                           // alias (rd1 dead after P7)
  float* svec = (float*)hwt_s;                   // alias (hwt dead after P6)
  float* lvec = (float*)(hwt_s + 256);
  int tid = threadIdx.x;
  int lane = tid & 63, w = tid >> 6;
  int r15 = lane & 15, kg = lane >> 4;
  int c = blockIdx.x >> 8, b = blockIdx.x & 255;
  int n = cnt_g[c];
  if (tid < 64) list_s[tid] = (tid < n) ? lists[c * 64 + tid] : 0;
  if (tid < 128) {
    a1d_s[tid] = a1d[c * 128 + tid];
    a1s_s[tid] = a1s[c * 128 + tid];
    b1_s[tid]  = b1[c * 128 + tid];
    ud2_s[tid] = ud2_g[c * 128 + tid];
    us2_s[tid] = us2_g[c * 128 + tid];
  }
  if (tid < 256) { e1d_s[tid] = 0.f; e1s_s[tid] = 0.f; }
  // neighbor chunk prefetch: thread (r,q) owns neighbors [q*16, q*16+16)
  int r = tid >> 2, q = tid & 3;
  int dg = deg_g[r];
  int t0 = q * 16;
  int ncnt = dg - t0; ncnt = (ncnt < 0) ? 0 : (ncnt > 16 ? 16 : ncnt);
  const uint32_t* np = (const uint32_t*)&nbr_g[r * 64 + t0];
  uint32_t nbw0 = np[0], nbw1 = np[1], nbw2 = np[2], nbw3 = np[3];
  __syncthreads();  // B0
  // P2: hW1 MFMA, wave = (mt = w&3 rows, nh = w>>2 col-pair), A from global.
  int mt = w & 3, nh = w >> 2;
  int colA = nh * 32 + r15, colB = colA + 16;
  const uint16_t* bptr = &W1T[((long)c * 128 + colA) * 256 + kg * 8];
  const uint16_t* arow = &EMB[((long)b * 256 + list_s[mt * 16 + r15]) * 256 + kg * 8];
  f32x4 acc0 = (f32x4){0.f, 0.f, 0.f, 0.f};
  f32x4 acc1 = (f32x4){0.f, 0.f, 0.f, 0.f};
  if (mt * 16 < n) {
    #pragma unroll
    for (int ks = 0; ks < 8; ++ks) {
      bf16x8 b0 = *(const bf16x8*)(bptr + ks * 32);
      bf16x8 b1f = *(const bf16x8*)(bptr + 16 * 256 + ks * 32);
      bf16x8 afr = *(const bf16x8*)(arow + ks * 32);
      acc0 = __builtin_amdgcn_mfma_f32_16x16x32_bf16(afr, b0, acc0, 0, 0, 0);
      acc1 = __builtin_amdgcn_mfma_f32_16x16x32_bf16(afr, b1f, acc1, 0, 0, 0);
    }
  }
  // P3: write hwt (transposed bf16); pd/ps fragment dots -> e2d_s/e2s_s temp
  {
    uint2 pA, pB;
    pA.x = (uint32_t)f2bf(acc0[0]) | ((uint32_t)f2bf(acc0[1]) << 16);
    pA.y = (uint32_t)f2bf(acc0[2]) | ((uint32_t)f2bf(acc0[3]) << 16);
    pB.x = (uint32_t)f2bf(acc1[0]) | ((uint32_t)f2bf(acc1[1]) << 16);
    pB.y = (uint32_t)f2bf(acc1[2]) | ((uint32_t)f2bf(acc1[3]) << 16);
    *(uint2*)&hwt_s[colA * 72 + mt * 16 + kg * 4] = pA;
    *(uint2*)&hwt_s[colB * 72 + mt * 16 + kg * 4] = pB;
    float adA = a1d_s[colA], adB = a1d_s[colB];
    float asA = a1s_s[colA], asB = a1s_s[colB];
    #pragma unroll
    for (int j = 0; j < 4; ++j) {
      float pd = acc0[j] * adA + acc1[j] * adB;
      float ps = acc0[j] * asA + acc1[j] * asB;
      pd += __shfl_xor(pd, 1); pd += __shfl_xor(pd, 2);
      pd += __shfl_xor(pd, 4); pd += __shfl_xor(pd, 8);
      ps += __shfl_xor(ps, 1); ps += __shfl_xor(ps, 2);
      ps += __shfl_xor(ps, 4); ps += __shfl_xor(ps, 8);
      if (r15 == 0) {
        int jm = mt * 16 + kg * 4 + j;
        e2d_s[nh * 64 + jm] = pd;   // temp pd partial
        e2s_s[nh * 64 + jm] = ps;   // temp ps partial
      }
    }
  }
  __syncthreads();  // B1
  // P4: zero alpha region; combine e1d/e1s for members
  for (int idx = tid; idx < 4608; idx += 1024)
    *(uint2*)&alpha_s[idx * 4] = (uint2){0u, 0u};
  if (tid < 64 && tid < n) {
    float sd = e2d_s[tid] + e2d_s[tid + 64] + e2d_s[tid + 128] + e2d_s[tid + 192];
    float ss = e2s_s[tid] + e2s_s[tid + 64] + e2s_s[tid + 128] + e2s_s[tid + 192];
    int rr = list_s[tid];
    e1d_s[rr] = sd;
    e1s_s[rr] = ss;
  }
  __syncthreads();  // B2
  // P5: alpha scatter + den1 (register-resident neighbor chunk)
  {
    float e1dv = e1d_s[r];
    float den = 0.f;
    #define NB_CHUNK(WORD, BASE)                                            \
      _Pragma("unroll")                                                     \
      for (int ii = 0; ii < 4; ++ii) {                                      \
        if (BASE + ii < ncnt) {                                             \
          int j = (int)((WORD >> (ii * 8)) & 255u);                         \
          float e = e1dv + e1s_s[j];                                        \
          e = fmaxf(e, 0.2f * e);                                           \
          e = fminf(e, 60.f);                                               \
          float wv = __expf(e);                                             \
          den += wv;                                                        \
          int mi = midx_g[c * 256 + j];                                     \
          if (mi >= 0) alpha_s[r * 72 + mi] = f2bf(wv);                     \
        }                                                                   \
      }
    NB_CHUNK(nbw0, 0) NB_CHUNK(nbw1, 4) NB_CHUNK(nbw2, 8) NB_CHUNK(nbw3, 12)
    #undef NB_CHUNK
    den += __shfl_xor(den, 1);
    den += __shfl_xor(den, 2);
    if (q == 0) rd1_s[r] = 1.0f / den;
  }
  __syncthreads();  // B3
  // P6: G = alpha @ hwt via MFMA. wave w -> rules w*16..+15, 8 n-tiles.
  f32x4 g[8];
  #pragma unroll
  for (int nt = 0; nt < 8; ++nt) g[nt] = (f32x4){0.f, 0.f, 0.f, 0.f};
  int kslices = (n > 32) ? 2 : 1;
  for (int ks = 0; ks < kslices; ++ks) {
    bf16x8 afr = *(const bf16x8*)&alpha_s[(w * 16 + r15) * 72 + ks * 32 + kg * 8];
    #pragma unroll
    for (int nt = 0; nt < 8; ++nt) {
      bf16x8 bfr = *(const bf16x8*)&hwt_s[(nt * 16 + r15) * 72 + ks * 32 + kg * 8];
      g[nt] = __builtin_amdgcn_mfma_f32_16x16x32_bf16(afr, bfr, g[nt], 0, 0, 0);
    }
  }
  // P7: epilogue: g = relu(G*rd1 + b1); e2 dots
  {
    float rd1v[4];
    #pragma unroll
    for (int j = 0; j < 4; ++j) rd1v[j] = rd1_s[w * 16 + kg * 4 + j];
    float ed[4] = {0.f, 0.f, 0.f, 0.f}, es[4] = {0.f, 0.f, 0.f, 0.f};
    #pragma unroll
    for (int nt = 0; nt < 8; ++nt) {
      float uf = ud2_s[nt * 16 + r15], sf = us2_s[nt * 16 + r15];
      float bf = b1_s[nt * 16 + r15];
      #pragma unroll
      for (int j = 0; j < 4; ++j) {
        float gv = fmaxf(g[nt][j] * rd1v[j] + bf, 0.f);
        g[nt][j] = gv;
        ed[j] += gv * uf;
        es[j] += gv * sf;
      }
    }
    __syncthreads();  // B4 (rd1 reads done; e2d/e2s temps dead -> real e2)
    #pragma unroll
    for (int j = 0; j < 4; ++j) {
      ed[j] += __shfl_xor(ed[j], 1); ed[j] += __shfl_xor(ed[j], 2);
      ed[j] += __shfl_xor(ed[j], 4); ed[j] += __shfl_xor(ed[j], 8);
      es[j] += __shfl_xor(es[j], 1); es[j] += __shfl_xor(es[j], 2);
      es[j] += __shfl_xor(es[j], 4); es[j] += __shfl_xor(es[j], 8);
      if (r15 == 0) {
        e2d_s[w * 16 + kg * 4 + j] = ed[j];
        e2s_s[w * 16 + kg * 4 + j] = es[j];
      }
    }
  }
  __syncthreads();  // B5
  // P8: den2 (register neighbor chunk)
  {
    float e2dv = e2d_s[r];
    float den2 = 0.f;
    #define NB_CHUNK(WORD, BASE)                                            \
      _Pragma("unroll")                                                     \
      for (int ii = 0; ii < 4; ++ii) {                                      \
        if (BASE + ii < ncnt) {                                             \
          int j = (int)((WORD >> (ii * 8)) & 255u);                         \
          float e = e2dv + e2s_s[j];                                        \
          e = fmaxf(e, 0.2f * e);                                           \
          e = fminf(e, 60.f);                                               \
          den2 += __expf(e);                                                \
        }                                                                   \
      }
    NB_CHUNK(nbw0, 0) NB_CHUNK(nbw1, 4) NB_CHUNK(nbw2, 8) NB_CHUNK(nbw3, 12)
    #undef NB_CHUNK
    den2 += __shfl_xor(den2, 1);
    den2 += __shfl_xor(den2, 2);
    if (q == 0) rd2_s[r] = 1.0f / den2;
  }
  __syncthreads();  // B6
  // P9: column weights wj[r] = sum_i alpha2[i,r]
  {
    float e2sv = e2s_s[r];
    float wj = 0.f;
    #define NB_CHUNK(WORD, BASE)                                            \
      _Pragma("unroll")                                                     \
      for (int ii = 0; ii < 4; ++ii) {                                      \
        if (BASE + ii < ncnt) {                                             \
          int i2 = (int)((WORD >> (ii * 8)) & 255u);                        \
          float e = e2d_s[i2] + e2sv;                                       \
          e = fmaxf(e, 0.2f * e);                                           \
          e = fminf(e, 60.f);                                               \
          wj += __expf(e) * rd2_s[i2];                                      \
        }                                                                   \
      }
    NB_CHUNK(nbw0, 0) NB_CHUNK(nbw1, 4) NB_CHUNK(nbw2, 8) NB_CHUNK(nbw3, 12)
    #undef NB_CHUNK
    wj += __shfl_xor(wj, 1);
    wj += __shfl_xor(wj, 2);
    if (q == 0) wj_s[r] = wj;
  }
  __syncthreads();  // B7
  // P10: t partials from live fragments (tpart aliases alpha, dead now)
  {
    float wjv[4];
    #pragma unroll
    for (int j = 0; j < 4; ++j) wjv[j] = wj_s[w * 16 + kg * 4 + j];
    #pragma unroll
    for (int nt = 0; nt < 8; ++nt) {
      float tp = wjv[0] * g[nt][0] + wjv[1] * g[nt][1] + wjv[2] * g[nt][2] + wjv[3] * g[nt][3];
      tp += __shfl_xor(tp, 16);
      tp += __shfl_xor(tp, 32);
      if (kg == 0) tpart[w][nt * 16 + r15] = tp;
    }
  }
  __syncthreads();  // B8
  // P11: t combine
  if (tid < 128) {
    float s = 0.f;
    #pragma unroll
    for (int w2 = 0; w2 < 16; ++w2) s += tpart[w2][tid];
    t_s[tid] = s;
  }
  __syncthreads();  // B9
  // P12: svec partials: all 1024 threads, coalesced W2 reads.
  {
    int col = tid & 63, fg = tid >> 6;
    float sp = 0.f;
    #pragma unroll
    for (int i = 0; i < 8; ++i) {
      int f = fg * 8 + i;
      sp += t_s[f] * W2[((long)c * 128 + f) * 64 + col];
    }
    tpart[fg][col] = sp;
  }
  __syncthreads();  // B10
  if (tid < 64) {
    float s = 256.0f * b2[c * 64 + tid];
    #pragma unroll
    for (int fg = 0; fg < 16; ++fg) s += tpart[fg][tid];
    svec[tid] = s;
  }
  __syncthreads();  // B11
  if (tid < 6) {
    float lg = 256.0f * bl[c * 6 + tid];
    for (int f = 0; f < 64; ++f) lg += svec[f] * Wl[((long)c * 64 + f) * 6 + tid];
    lvec[tid] = lg;
  }
  __syncthreads();  // B12
  if (tid == 0) {
    float mm = lvec[0];
    for (int k2 = 1; k2 < 6; ++k2) mm = fmaxf(mm, lvec[k2]);
    float ss = 0.f;
    for (int k2 = 0; k2 < 6; ++k2) ss += __expf(lvec[k2] - mm);
    float lse = mm + __logf(ss);
    for (int k2 = 0; k2 < 6; ++k2) out[((long)c * 256 + b) * 6 + k2] = lvec[k2] - lse;
  }
}

// ---------------------------------------------------------------------------
extern "C" void kernel_launch(void* const* d_in, const int* in_sizes, int n_in,
                              void* d_out, int out_size, void* d_ws, size_t ws_size,
                              hipStream_t stream)
{
  const float* vis   = (const float*)d_in[0];
  const float* basic = (const float*)d_in[1];
  const float* cruc  = (const float*)d_in[2];
  const float* Wtb   = (const float*)d_in[3];
  const float* btb   = (const float*)d_in[4];
  const float* Wtk   = (const float*)d_in[5];
  const float* btk   = (const float*)d_in[6];
  const float* Wq    = (const float*)d_in[7];
  const float* bq    = (const float*)d_in[8];
  const float* Wk    = (const float*)d_in[9];
  const float* bk    = (const float*)d_in[10];
  const float* Wv    = (const float*)d_in[11];
  const float* bv    = (const float*)d_in[12];
  const float* Wo    = (const float*)d_in[13];
  const float* bo    = (const float*)d_in[14];
  const float* W1    = (const float*)d_in[15];
  const float* a1s   = (const float*)d_in[16];
  const float* a1d   = (const float*)d_in[17];
  const float* b1    = (const float*)d_in[18];
  const float* W2    = (const float*)d_in[19];
  const float* a2s   = (const float*)d_in[20];
  const float* a2d   = (const float*)d_in[21];
  const float* b2    = (const float*)d_in[22];
  const float* Wl    = (const float*)d_in[23];
  const float* bl    = (const float*)d_in[24];
  const void*  adj   = d_in[25];
  const int*   mask  = (const int*)d_in[26];
  float* out = (float*)d_out;
  char* ws = (char*)d_ws;

  uint16_t* QBF  = (uint16_t*)(ws + 0);         // 131072
  uint32_t* ADJ  = (uint32_t*)(ws + 262144);    // 8192
  int*      CLS  = (int*)(ws + 270336);         // 1024
  int*      LST  = (int*)(ws + 271360);         // 2560
  int*      CNT  = (int*)(ws + 273920);         // 64
  int*      DEG  = (int*)(ws + 273984);         // 1024
  uint8_t*  NBR  = (uint8_t*)(ws + 275008);     // 16384
  int8_t*   MIDX = (int8_t*)(ws + 291392);      // 2560
  float*    UD2  = (float*)(ws + 293952);       // 5120
  float*    US2  = (float*)(ws + 299072);       // 5120
  uint16_t* WOT  = (uint16_t*)(ws + 304192);    // 131072
  uint16_t* WKVT = (uint16_t*)(ws + 435264);    // 262144
  uint16_t* W1T  = (uint16_t*)(ws + 697408);    // 655360
  uint16_t* KX   = (uint16_t*)(ws + 1352768);   // 8388608
  uint16_t* VX   = (uint16_t*)(ws + 9741376);   // 8388608
  uint16_t* EMB  = (uint16_t*)(ws + 18129984);  // 33554432 -> total ~49.3 MiB

  hipLaunchKernelGGL(k_front, dim3(2443), dim3(256), 0, stream,
                     adj, mask, W2, a2s, a2d, ADJ, CLS, LST, CNT, DEG, NBR, MIDX,
                     UD2, US2,
                     Wo, Wk, Wv, W1, WOT, WKVT, W1T,
                     basic, cruc, Wtb, btb, Wtk, btk, Wq, bq, QBF,
                     vis, bk, bv, KX, VX);
  hipLaunchKernelGGL(k_attn, dim3(512), dim3(512), 0, stream, QBF, KX, VX, EMB);
  hipLaunchKernelGGL(k_wo, dim3(1024), dim3(256), 0, stream, EMB, WOT, bo);
  hipLaunchKernelGGL(k_gat, dim3(2560), dim3(1024), 0, stream,
                     EMB, W1T, a1d, a1s, LST, CNT, DEG, NBR, MIDX,
                     b1, UD2, US2, W2, b2, Wl, bl, out);
}